// Round 1
// baseline (928.315 us; speedup 1.0000x reference)
//
#include <hip/hip_runtime.h>
#include <cstdint>
#include <cstddef>

#define NEG_SLOPE 0.2f

// ---------------- CSR build ----------------
__global__ void k_init_counts(int* counts, int N) {
  int n = blockIdx.x * blockDim.x + threadIdx.x;
  if (n < N) counts[n] = 1;  // self loop
}

__global__ void k_count(const int* __restrict__ dst, int E, int* counts) {
  int e = blockIdx.x * blockDim.x + threadIdx.x;
  if (e < E) atomicAdd(&counts[dst[e]], 1);
}

__global__ __launch_bounds__(1024) void k_scan1(const int* __restrict__ counts, int N,
                                                int* __restrict__ row_ptr, int* __restrict__ part) {
  __shared__ int tmp[1024];
  int t = threadIdx.x;
  int i = blockIdx.x * 1024 + t;
  int v = (i < N) ? counts[i] : 0;
  tmp[t] = v;
  __syncthreads();
  for (int off = 1; off < 1024; off <<= 1) {
    int u = (t >= off) ? tmp[t - off] : 0;
    __syncthreads();
    tmp[t] += u;
    __syncthreads();
  }
  if (i < N) row_ptr[i + 1] = tmp[t];
  if (t == 1023) part[blockIdx.x] = tmp[t];
}

__global__ void k_scan2(int* part, int nb, int* row_ptr) {
  if (threadIdx.x == 0 && blockIdx.x == 0) {
    int run = 0;
    for (int b = 0; b < nb; b++) { int v = part[b]; part[b] = run; run += v; }
    row_ptr[0] = 0;
  }
}

__global__ __launch_bounds__(1024) void k_scan3(int* __restrict__ row_ptr,
                                                const int* __restrict__ part, int N) {
  int i = blockIdx.x * 1024 + threadIdx.x;
  if (i < N) row_ptr[i + 1] += part[blockIdx.x];
}

__global__ void k_fill_self(const int* __restrict__ row_ptr, int* __restrict__ fill_ptr,
                            int* __restrict__ col, int N) {
  int n = blockIdx.x * blockDim.x + threadIdx.x;
  if (n < N) { int p = row_ptr[n]; col[p] = n; fill_ptr[n] = p + 1; }
}

__global__ void k_fill(const int* __restrict__ src, const int* __restrict__ dst, int E,
                       int* fill_ptr, int* __restrict__ col) {
  int e = blockIdx.x * blockDim.x + threadIdx.x;
  if (e < E) { int p = atomicAdd(&fill_ptr[dst[e]], 1); col[p] = src[e]; }
}

// ---------------- Tiled fp32 GEMM: C[M x Nc] = A[M x K] @ W[K x Nc] (+bias, +relu) ----------------
#define CK 64
__global__ __launch_bounds__(256) void k_gemm(const float* __restrict__ A,
                                              const float* __restrict__ W,
                                              const float* __restrict__ bias,
                                              float* __restrict__ C,
                                              int M, int K, int Nc, int relu) {
  __shared__ float As[32][CK + 4];
  __shared__ float Ws[CK][128];
  int t = threadIdx.x;
  int tx = t & 31;   // col4 index: cols tx*4 .. tx*4+3
  int ty = t >> 5;   // 0..7 -> rows {ty, ty+8, ty+16, ty+24}
  int rowbase = blockIdx.x * 32;
  int colbase = blockIdx.y * 128;
  float4 acc[4];
  acc[0] = acc[1] = acc[2] = acc[3] = make_float4(0.f, 0.f, 0.f, 0.f);

  for (int kb = 0; kb < K; kb += CK) {
    for (int idx = t * 4; idx < 32 * CK; idx += 256 * 4) {
      int r = idx / CK, kk = idx % CK;
      int gr = rowbase + r;
      float4 v = make_float4(0.f, 0.f, 0.f, 0.f);
      if (gr < M) v = *(const float4*)&A[(size_t)gr * K + kb + kk];
      *(float4*)&As[r][kk] = v;
    }
    for (int idx = t * 4; idx < CK * 128; idx += 256 * 4) {
      int kk = idx >> 7, cc = idx & 127;
      *(float4*)&Ws[kk][cc] = *(const float4*)&W[(size_t)(kb + kk) * Nc + colbase + cc];
    }
    __syncthreads();
#pragma unroll
    for (int kk = 0; kk < CK; kk++) {
      float4 w = *(float4*)&Ws[kk][tx * 4];
#pragma unroll
      for (int r = 0; r < 4; r++) {
        float a = As[ty + 8 * r][kk];
        acc[r].x += a * w.x; acc[r].y += a * w.y; acc[r].z += a * w.z; acc[r].w += a * w.w;
      }
    }
    __syncthreads();
  }

  float4 bv = make_float4(0.f, 0.f, 0.f, 0.f);
  if (bias) bv = *(const float4*)&bias[colbase + tx * 4];
#pragma unroll
  for (int r = 0; r < 4; r++) {
    int gr = rowbase + ty + 8 * r;
    if (gr < M) {
      float4 o = acc[r];
      o.x += bv.x; o.y += bv.y; o.z += bv.z; o.w += bv.w;
      if (relu) { o.x = fmaxf(o.x, 0.f); o.y = fmaxf(o.y, 0.f); o.z = fmaxf(o.z, 0.f); o.w = fmaxf(o.w, 0.f); }
      *(float4*)&C[(size_t)gr * Nc + colbase + tx * 4] = o;
    }
  }
}

// ---------------- per-node s = h.a_src, d = h.a_dst ----------------
__global__ __launch_bounds__(256) void k_sd(const float* __restrict__ h,
                                            const float* __restrict__ asrc,
                                            const float* __restrict__ adst,
                                            float* __restrict__ s, float* __restrict__ d, int N) {
  int wid = (int)((blockIdx.x * (size_t)blockDim.x + threadIdx.x) >> 6);
  int lane = threadIdx.x & 63;
  if (wid >= N) return;
  float2 h2 = *(const float2*)&h[(size_t)wid * 128 + lane * 2];
  float2 a2 = *(const float2*)&asrc[lane * 2];
  float2 b2 = *(const float2*)&adst[lane * 2];
  float ps = h2.x * a2.x + h2.y * a2.y;
  float pd = h2.x * b2.x + h2.y * b2.y;
  for (int off = 32; off; off >>= 1) {
    ps += __shfl_xor(ps, off);
    pd += __shfl_xor(pd, off);
  }
  if (lane == 0) { s[wid] = ps; d[wid] = pd; }
}

// ---------------- per-node segment-softmax aggregation (one wave per dst node) ----------------
__global__ __launch_bounds__(256) void k_agg(const float* __restrict__ h,
                                             const float* __restrict__ sv,
                                             const float* __restrict__ dv,
                                             const int* __restrict__ row_ptr,
                                             const int* __restrict__ col,
                                             const float* __restrict__ bias,
                                             float* __restrict__ out, int N, int relu) {
  int wid = (int)((blockIdx.x * (size_t)blockDim.x + threadIdx.x) >> 6);
  int lane = threadIdx.x & 63;
  if (wid >= N) return;
  int beg = row_ptr[wid], end = row_ptr[wid + 1];
  float dn = dv[wid];

  // pass A: segment max of leaky_relu(s[src] + d[dst])
  float m = -1e30f;
  for (int j = beg + lane; j < end; j += 64) {
    float e = sv[col[j]] + dn;
    e = (e > 0.f) ? e : NEG_SLOPE * e;
    m = fmaxf(m, e);
  }
  for (int off = 32; off; off >>= 1) m = fmaxf(m, __shfl_xor(m, off));

  // pass B: acc = sum exp(e-m) * h[src]; dsum = sum exp(e-m)
  float2 acc = make_float2(0.f, 0.f);
  float dsum = 0.f;
  for (int jb = beg; jb < end; jb += 64) {
    int j = jb + lane;
    float w = 0.f;
    int sn = 0;
    if (j < end) {
      sn = col[j];
      float e = sv[sn] + dn;
      e = (e > 0.f) ? e : NEG_SLOPE * e;
      w = __expf(e - m);
    }
    dsum += w;
    int cnt = min(64, end - jb);
    for (int tt = 0; tt < cnt; ++tt) {
      float wt = __shfl(w, tt);
      int st = __shfl(sn, tt);
      float2 hv = *(const float2*)&h[(size_t)st * 128 + lane * 2];
      acc.x += wt * hv.x;
      acc.y += wt * hv.y;
    }
  }
  for (int off = 32; off; off >>= 1) dsum += __shfl_xor(dsum, off);
  float inv = 1.f / dsum;
  float2 bv = *(const float2*)&bias[lane * 2];
  float o0 = acc.x * inv + bv.x;
  float o1 = acc.y * inv + bv.y;
  if (relu) { o0 = fmaxf(o0, 0.f); o1 = fmaxf(o1, 0.f); }
  *(float2*)&out[(size_t)wid * 128 + lane * 2] = make_float2(o0, o1);
}

// ---------------- batch boundaries (batch is sorted) ----------------
__global__ void k_bounds(const int* __restrict__ batch, int N, int B, int* __restrict__ gstart) {
  int n = blockIdx.x * blockDim.x + threadIdx.x;
  if (n >= N) return;
  int cur = batch[n];
  if (n == 0) {
    for (int g = 0; g <= cur; g++) gstart[g] = 0;
  } else {
    int prev = batch[n - 1];
    for (int g = prev + 1; g <= cur; g++) gstart[g] = n;
  }
  if (n == N - 1) {
    for (int g = cur + 1; g <= B; g++) gstart[g] = N;
  }
}

// ---------------- mean pool + relu ----------------
__global__ __launch_bounds__(128) void k_pool(const float* __restrict__ h,
                                              const int* __restrict__ gstart,
                                              float* __restrict__ pooled, int B) {
  int b = blockIdx.x, c = threadIdx.x;
  int s0 = gstart[b], s1 = gstart[b + 1];
  float acc = 0.f;
  for (int n = s0; n < s1; n++) acc += h[(size_t)n * 128 + c];
  int cnt = s1 - s0;
  float p = acc / (float)(cnt > 0 ? cnt : 1);
  pooled[b * 128 + c] = fmaxf(p, 0.f);
}

extern "C" void kernel_launch(void* const* d_in, const int* in_sizes, int n_in,
                              void* d_out, int out_size, void* d_ws, size_t ws_size,
                              hipStream_t stream) {
  const float* x     = (const float*)d_in[0];
  const int*   ei    = (const int*)d_in[1];
  const int*   batch = (const int*)d_in[3];
  const float* W1 = (const float*)d_in[4];
  const float* as1 = (const float*)d_in[5];
  const float* ad1 = (const float*)d_in[6];
  const float* b1 = (const float*)d_in[7];
  const float* W2 = (const float*)d_in[8];
  const float* as2 = (const float*)d_in[9];
  const float* ad2 = (const float*)d_in[10];
  const float* b2 = (const float*)d_in[11];
  const float* W3 = (const float*)d_in[12];
  const float* as3 = (const float*)d_in[13];
  const float* ad3 = (const float*)d_in[14];
  const float* b3 = (const float*)d_in[15];
  const float* Wf1 = (const float*)d_in[16];
  const float* bf1 = (const float*)d_in[17];
  const float* Wf2 = (const float*)d_in[18];
  const float* bf2 = (const float*)d_in[19];

  const int N = in_sizes[0] / 128;
  const int E = in_sizes[1] / 2;
  const int H = in_sizes[17];
  const int B = out_size / 128;

  char* base = (char*)d_ws;
  size_t off = 0;
  auto carve = [&](size_t bytes) -> void* {
    off = (off + 255) & ~(size_t)255;
    void* p = base + off;
    off += bytes;
    return p;
  };
  int* counts   = (int*)carve((size_t)N * 4);
  int* row_ptr  = (int*)carve((size_t)(N + 1) * 4);
  int* fill_ptr = (int*)carve((size_t)N * 4);
  int* col      = (int*)carve((size_t)(E + N) * 4);
  int* part     = (int*)carve(1024 * 4);
  int* gstart   = (int*)carve((size_t)(B + 1) * 4);
  float* sbuf   = (float*)carve((size_t)N * 4);
  float* dbuf   = (float*)carve((size_t)N * 4);
  float* hbuf   = (float*)carve((size_t)N * 128 * 4);
  float* abuf   = (float*)carve((size_t)N * 128 * 4);
  float* pooled = (float*)carve((size_t)B * 128 * 4);
  float* o1     = (float*)carve((size_t)B * H * 4);

  const int* srcp = ei;
  const int* dstp = ei + E;
  const int nb = (N + 1023) / 1024;

  hipLaunchKernelGGL(k_init_counts, dim3((N + 255) / 256), dim3(256), 0, stream, counts, N);
  hipLaunchKernelGGL(k_count, dim3((E + 255) / 256), dim3(256), 0, stream, dstp, E, counts);
  hipLaunchKernelGGL(k_scan1, dim3(nb), dim3(1024), 0, stream, counts, N, row_ptr, part);
  hipLaunchKernelGGL(k_scan2, dim3(1), dim3(64), 0, stream, part, nb, row_ptr);
  hipLaunchKernelGGL(k_scan3, dim3(nb), dim3(1024), 0, stream, row_ptr, part, N);
  hipLaunchKernelGGL(k_fill_self, dim3((N + 255) / 256), dim3(256), 0, stream, row_ptr, fill_ptr, col, N);
  hipLaunchKernelGGL(k_fill, dim3((E + 255) / 256), dim3(256), 0, stream, srcp, dstp, E, fill_ptr, col);
  hipLaunchKernelGGL(k_bounds, dim3((N + 255) / 256), dim3(256), 0, stream, batch, N, B, gstart);

  const float* Wl[3] = {W1, W2, W3};
  const float* al[3] = {as1, as2, as3};
  const float* dl[3] = {ad1, ad2, ad3};
  const float* bl[3] = {b1, b2, b3};
  const float* cur = x;
  for (int L = 0; L < 3; L++) {
    hipLaunchKernelGGL(k_gemm, dim3((N + 31) / 32, 1), dim3(256), 0, stream,
                       cur, Wl[L], (const float*)nullptr, hbuf, N, 128, 128, 0);
    hipLaunchKernelGGL(k_sd, dim3((N + 3) / 4), dim3(256), 0, stream,
                       hbuf, al[L], dl[L], sbuf, dbuf, N);
    hipLaunchKernelGGL(k_agg, dim3((N + 3) / 4), dim3(256), 0, stream,
                       hbuf, sbuf, dbuf, row_ptr, col, bl[L], abuf, N, (L > 0) ? 1 : 0);
    cur = abuf;
  }

  hipLaunchKernelGGL(k_pool, dim3(B), dim3(128), 0, stream, abuf, gstart, pooled, B);
  hipLaunchKernelGGL(k_gemm, dim3((B + 31) / 32, H / 128), dim3(256), 0, stream,
                     pooled, Wf1, bf1, o1, B, 128, H, 1);
  hipLaunchKernelGGL(k_gemm, dim3((B + 31) / 32, 1), dim3(256), 0, stream,
                     o1, Wf2, bf2, (float*)d_out, B, H, 128, 0);
}

// Round 2
// 825.988 us; speedup vs baseline: 1.1239x; 1.1239x over previous
//
#include <hip/hip_runtime.h>
#include <cstdint>
#include <cstddef>

#define NEG_SLOPE 0.2f

__device__ __forceinline__ unsigned enc_f(float f) {
  unsigned u = __float_as_uint(f);
  return (u & 0x80000000u) ? ~u : (u | 0x80000000u);
}
__device__ __forceinline__ float dec_f(unsigned u) {
  return (u & 0x80000000u) ? __uint_as_float(u ^ 0x80000000u) : __uint_as_float(~u);
}

// ---------------- CSR build ----------------
__global__ void k_init(int* counts, unsigned* maxPart, int N) {
  int n = blockIdx.x * blockDim.x + threadIdx.x;
  if (n < N) counts[n] = 1;  // self loop
  if (n < 768) maxPart[n] = 0u;  // < enc of any finite float
}

// rank trick: the atomicAdd return value IS the within-bucket rank (starts at 1; slot 0 = self loop)
__global__ void k_count_rank(const int* __restrict__ dst, int E,
                             int* counts, int* __restrict__ rank) {
  int e = blockIdx.x * blockDim.x + threadIdx.x;
  if (e < E) rank[e] = atomicAdd(&counts[dst[e]], 1);
}

__global__ __launch_bounds__(1024) void k_scan1(const int* __restrict__ counts, int N,
                                                int* __restrict__ row_ptr, int* __restrict__ part) {
  __shared__ int tmp[1024];
  int t = threadIdx.x;
  int i = blockIdx.x * 1024 + t;
  int v = (i < N) ? counts[i] : 0;
  tmp[t] = v;
  __syncthreads();
  for (int off = 1; off < 1024; off <<= 1) {
    int u = (t >= off) ? tmp[t - off] : 0;
    __syncthreads();
    tmp[t] += u;
    __syncthreads();
  }
  if (i < N) row_ptr[i + 1] = tmp[t];
  if (t == 1023) part[blockIdx.x] = tmp[t];
}

__global__ void k_scan2(int* part, int nb, int* row_ptr) {
  if (threadIdx.x == 0 && blockIdx.x == 0) {
    int run = 0;
    for (int b = 0; b < nb; b++) { int v = part[b]; part[b] = run; run += v; }
    row_ptr[0] = 0;
  }
}

__global__ __launch_bounds__(1024) void k_scan3(int* __restrict__ row_ptr,
                                                const int* __restrict__ part, int N) {
  int i = blockIdx.x * 1024 + threadIdx.x;
  if (i < N) row_ptr[i + 1] += part[blockIdx.x];
}

__global__ void k_fill_self(const int* __restrict__ row_ptr, int* __restrict__ col, int N) {
  int n = blockIdx.x * blockDim.x + threadIdx.x;
  if (n < N) col[row_ptr[n]] = n;
}

// no atomic: position = row_ptr[dst] + rank
__global__ void k_fill(const int* __restrict__ src, const int* __restrict__ dst,
                       const int* __restrict__ rank, int E,
                       const int* __restrict__ row_ptr, int* __restrict__ col) {
  int e = blockIdx.x * blockDim.x + threadIdx.x;
  if (e < E) col[row_ptr[dst[e]] + rank[e]] = src[e];
}

// ---------------- Tiled fp32 GEMM: C[M x Nc] = A[M x K] @ W[K x Nc] (+bias, +relu) ----------------
#define CK 64
__global__ __launch_bounds__(256) void k_gemm(const float* __restrict__ A,
                                              const float* __restrict__ W,
                                              const float* __restrict__ bias,
                                              float* __restrict__ C,
                                              int M, int K, int Nc, int relu) {
  __shared__ float As[32][CK + 4];
  __shared__ float Ws[CK][128];
  int t = threadIdx.x;
  int tx = t & 31;
  int ty = t >> 5;
  int rowbase = blockIdx.x * 32;
  int colbase = blockIdx.y * 128;
  float4 acc[4];
  acc[0] = acc[1] = acc[2] = acc[3] = make_float4(0.f, 0.f, 0.f, 0.f);

  for (int kb = 0; kb < K; kb += CK) {
    for (int idx = t * 4; idx < 32 * CK; idx += 256 * 4) {
      int r = idx / CK, kk = idx % CK;
      int gr = rowbase + r;
      float4 v = make_float4(0.f, 0.f, 0.f, 0.f);
      if (gr < M) v = *(const float4*)&A[(size_t)gr * K + kb + kk];
      *(float4*)&As[r][kk] = v;
    }
    for (int idx = t * 4; idx < CK * 128; idx += 256 * 4) {
      int kk = idx >> 7, cc = idx & 127;
      *(float4*)&Ws[kk][cc] = *(const float4*)&W[(size_t)(kb + kk) * Nc + colbase + cc];
    }
    __syncthreads();
#pragma unroll
    for (int kk = 0; kk < CK; kk++) {
      float4 w = *(float4*)&Ws[kk][tx * 4];
#pragma unroll
      for (int r = 0; r < 4; r++) {
        float a = As[ty + 8 * r][kk];
        acc[r].x += a * w.x; acc[r].y += a * w.y; acc[r].z += a * w.z; acc[r].w += a * w.w;
      }
    }
    __syncthreads();
  }

  float4 bv = make_float4(0.f, 0.f, 0.f, 0.f);
  if (bias) bv = *(const float4*)&bias[colbase + tx * 4];
#pragma unroll
  for (int r = 0; r < 4; r++) {
    int gr = rowbase + ty + 8 * r;
    if (gr < M) {
      float4 o = acc[r];
      o.x += bv.x; o.y += bv.y; o.z += bv.z; o.w += bv.w;
      if (relu) { o.x = fmaxf(o.x, 0.f); o.y = fmaxf(o.y, 0.f); o.z = fmaxf(o.z, 0.f); o.w = fmaxf(o.w, 0.f); }
      *(float4*)&C[(size_t)gr * Nc + colbase + tx * 4] = o;
    }
  }
}

// ---------------- per-node s = h.a_src, d = h.a_dst, plus partial global max(s) ----------------
__global__ __launch_bounds__(256) void k_sd(const float* __restrict__ h,
                                            const float* __restrict__ asrc,
                                            const float* __restrict__ adst,
                                            float* __restrict__ s, float* __restrict__ d,
                                            unsigned* __restrict__ maxSlot, int N) {
  __shared__ float smx[4];
  int t = threadIdx.x;
  int w = t >> 6, lane = t & 63;
  int wid = blockIdx.x * 4 + w;
  float ps = -1e30f, pd = 0.f;
  if (wid < N) {
    float2 h2 = *(const float2*)&h[(size_t)wid * 128 + lane * 2];
    float2 a2 = *(const float2*)&asrc[lane * 2];
    float2 b2 = *(const float2*)&adst[lane * 2];
    ps = h2.x * a2.x + h2.y * a2.y;
    pd = h2.x * b2.x + h2.y * b2.y;
    for (int off = 32; off; off >>= 1) {
      ps += __shfl_xor(ps, off);
      pd += __shfl_xor(pd, off);
    }
    if (lane == 0) { s[wid] = ps; d[wid] = pd; }
  }
  if (lane == 0) smx[w] = (wid < N) ? ps : -1e30f;
  __syncthreads();
  if (t == 0) {
    float mx = fmaxf(fmaxf(smx[0], smx[1]), fmaxf(smx[2], smx[3]));
    atomicMax(&maxSlot[blockIdx.x & 255], enc_f(mx));
  }
}

// ---------------- single-pass segment-softmax aggregation (one wave / dst node, 4 edges in flight) ----
__global__ __launch_bounds__(256) void k_agg(const float* __restrict__ h,
                                             const float* __restrict__ sv,
                                             const float* __restrict__ dv,
                                             const int* __restrict__ row_ptr,
                                             const int* __restrict__ col,
                                             const float* __restrict__ bias,
                                             const unsigned* __restrict__ maxSlot,
                                             float* __restrict__ out, int N, int relu) {
  int wid = (int)((blockIdx.x * (size_t)blockDim.x + threadIdx.x) >> 6);
  int lane = threadIdx.x & 63;
  if (wid >= N) return;

  // wave-local reduce of the 256 partial-max slots -> global max(s)
  unsigned mp = max(max(maxSlot[lane], maxSlot[lane + 64]),
                    max(maxSlot[lane + 128], maxSlot[lane + 192]));
  for (int off = 32; off; off >>= 1) mp = max(mp, __shfl_xor(mp, off));
  float maxS = dec_f(mp);

  int beg = row_ptr[wid], end = row_ptr[wid + 1];
  float dn = dv[wid];
  float m = maxS + dn;
  m = (m > 0.f) ? m : NEG_SLOPE * m;  // valid upper bound (leaky_relu monotone)

  int quad = lane >> 4, sub = lane & 15;
  float acc[8];
#pragma unroll
  for (int k = 0; k < 8; k++) acc[k] = 0.f;
  float dsum = 0.f;

  for (int jb = beg; jb < end; jb += 64) {
    int j = jb + lane;
    float wgt = 0.f;
    int sn = 0;
    if (j < end) {
      sn = col[j];
      float e = sv[sn] + dn;
      e = (e > 0.f) ? e : NEG_SLOPE * e;
      wgt = __expf(e - m);
    }
    dsum += wgt;
    int rem = end - jb;
    int myn = min(16, max(0, rem - (quad << 4)));
    for (int tt = 0; tt < myn; tt++) {
      int sl = (quad << 4) + tt;
      float wt = __shfl(wgt, sl);
      int st = __shfl(sn, sl);
      const float* hp = &h[(size_t)st * 128 + sub * 8];
      float4 h0 = *(const float4*)hp;
      float4 h1 = *(const float4*)(hp + 4);
      acc[0] += wt * h0.x; acc[1] += wt * h0.y; acc[2] += wt * h0.z; acc[3] += wt * h0.w;
      acc[4] += wt * h1.x; acc[5] += wt * h1.y; acc[6] += wt * h1.z; acc[7] += wt * h1.w;
    }
  }
  for (int off = 32; off; off >>= 1) dsum += __shfl_xor(dsum, off);
#pragma unroll
  for (int k = 0; k < 8; k++) {
    acc[k] += __shfl_xor(acc[k], 32);
    acc[k] += __shfl_xor(acc[k], 16);
  }
  if (lane < 16) {
    float inv = 1.f / dsum;
    float4 b0 = *(const float4*)&bias[sub * 8];
    float4 b1 = *(const float4*)&bias[sub * 8 + 4];
    float4 o0, o1;
    o0.x = acc[0] * inv + b0.x; o0.y = acc[1] * inv + b0.y;
    o0.z = acc[2] * inv + b0.z; o0.w = acc[3] * inv + b0.w;
    o1.x = acc[4] * inv + b1.x; o1.y = acc[5] * inv + b1.y;
    o1.z = acc[6] * inv + b1.z; o1.w = acc[7] * inv + b1.w;
    if (relu) {
      o0.x = fmaxf(o0.x, 0.f); o0.y = fmaxf(o0.y, 0.f); o0.z = fmaxf(o0.z, 0.f); o0.w = fmaxf(o0.w, 0.f);
      o1.x = fmaxf(o1.x, 0.f); o1.y = fmaxf(o1.y, 0.f); o1.z = fmaxf(o1.z, 0.f); o1.w = fmaxf(o1.w, 0.f);
    }
    float* op = &out[(size_t)wid * 128 + sub * 8];
    *(float4*)op = o0;
    *(float4*)(op + 4) = o1;
  }
}

// ---------------- batch boundaries (batch is sorted) ----------------
__global__ void k_bounds(const int* __restrict__ batch, int N, int B, int* __restrict__ gstart) {
  int n = blockIdx.x * blockDim.x + threadIdx.x;
  if (n >= N) return;
  int cur = batch[n];
  if (n == 0) {
    for (int g = 0; g <= cur; g++) gstart[g] = 0;
  } else {
    int prev = batch[n - 1];
    for (int g = prev + 1; g <= cur; g++) gstart[g] = n;
  }
  if (n == N - 1) {
    for (int g = cur + 1; g <= B; g++) gstart[g] = N;
  }
}

// ---------------- mean pool + relu ----------------
__global__ __launch_bounds__(128) void k_pool(const float* __restrict__ h,
                                              const int* __restrict__ gstart,
                                              float* __restrict__ pooled, int B) {
  int b = blockIdx.x, c = threadIdx.x;
  int s0 = gstart[b], s1 = gstart[b + 1];
  float acc = 0.f;
  for (int n = s0; n < s1; n++) acc += h[(size_t)n * 128 + c];
  int cnt = s1 - s0;
  float p = acc / (float)(cnt > 0 ? cnt : 1);
  pooled[b * 128 + c] = fmaxf(p, 0.f);
}

extern "C" void kernel_launch(void* const* d_in, const int* in_sizes, int n_in,
                              void* d_out, int out_size, void* d_ws, size_t ws_size,
                              hipStream_t stream) {
  const float* x     = (const float*)d_in[0];
  const int*   ei    = (const int*)d_in[1];
  const int*   batch = (const int*)d_in[3];
  const float* W1 = (const float*)d_in[4];
  const float* as1 = (const float*)d_in[5];
  const float* ad1 = (const float*)d_in[6];
  const float* b1 = (const float*)d_in[7];
  const float* W2 = (const float*)d_in[8];
  const float* as2 = (const float*)d_in[9];
  const float* ad2 = (const float*)d_in[10];
  const float* b2 = (const float*)d_in[11];
  const float* W3 = (const float*)d_in[12];
  const float* as3 = (const float*)d_in[13];
  const float* ad3 = (const float*)d_in[14];
  const float* b3 = (const float*)d_in[15];
  const float* Wf1 = (const float*)d_in[16];
  const float* bf1 = (const float*)d_in[17];
  const float* Wf2 = (const float*)d_in[18];
  const float* bf2 = (const float*)d_in[19];

  const int N = in_sizes[0] / 128;
  const int E = in_sizes[1] / 2;
  const int H = in_sizes[17];
  const int B = out_size / 128;

  char* base = (char*)d_ws;
  size_t off = 0;
  auto carve = [&](size_t bytes) -> void* {
    off = (off + 255) & ~(size_t)255;
    void* p = base + off;
    off += bytes;
    return p;
  };
  int* counts   = (int*)carve((size_t)N * 4);
  int* row_ptr  = (int*)carve((size_t)(N + 1) * 4);
  int* rank     = (int*)carve((size_t)E * 4);
  int* col      = (int*)carve((size_t)(E + N) * 4);
  int* part     = (int*)carve(1024 * 4);
  int* gstart   = (int*)carve((size_t)(B + 1) * 4);
  unsigned* maxPart = (unsigned*)carve(768 * 4);
  float* sbuf   = (float*)carve((size_t)N * 4);
  float* dbuf   = (float*)carve((size_t)N * 4);
  float* hbuf   = (float*)carve((size_t)N * 128 * 4);
  float* abuf   = (float*)carve((size_t)N * 128 * 4);
  float* pooled = (float*)carve((size_t)B * 128 * 4);
  float* o1     = (float*)carve((size_t)B * H * 4);

  const int* srcp = ei;
  const int* dstp = ei + E;
  const int nb = (N + 1023) / 1024;

  hipLaunchKernelGGL(k_init, dim3((N + 255) / 256), dim3(256), 0, stream, counts, maxPart, N);
  hipLaunchKernelGGL(k_count_rank, dim3((E + 255) / 256), dim3(256), 0, stream, dstp, E, counts, rank);
  hipLaunchKernelGGL(k_scan1, dim3(nb), dim3(1024), 0, stream, counts, N, row_ptr, part);
  hipLaunchKernelGGL(k_scan2, dim3(1), dim3(64), 0, stream, part, nb, row_ptr);
  hipLaunchKernelGGL(k_scan3, dim3(nb), dim3(1024), 0, stream, row_ptr, part, N);
  hipLaunchKernelGGL(k_fill_self, dim3((N + 255) / 256), dim3(256), 0, stream, row_ptr, col, N);
  hipLaunchKernelGGL(k_fill, dim3((E + 255) / 256), dim3(256), 0, stream, srcp, dstp, rank, E, row_ptr, col);
  hipLaunchKernelGGL(k_bounds, dim3((N + 255) / 256), dim3(256), 0, stream, batch, N, B, gstart);

  const float* Wl[3] = {W1, W2, W3};
  const float* al[3] = {as1, as2, as3};
  const float* dl[3] = {ad1, ad2, ad3};
  const float* bl[3] = {b1, b2, b3};
  const float* cur = x;
  for (int L = 0; L < 3; L++) {
    hipLaunchKernelGGL(k_gemm, dim3((N + 31) / 32, 1), dim3(256), 0, stream,
                       cur, Wl[L], (const float*)nullptr, hbuf, N, 128, 128, 0);
    hipLaunchKernelGGL(k_sd, dim3((N + 3) / 4), dim3(256), 0, stream,
                       hbuf, al[L], dl[L], sbuf, dbuf, maxPart + L * 256, N);
    hipLaunchKernelGGL(k_agg, dim3((N + 3) / 4), dim3(256), 0, stream,
                       hbuf, sbuf, dbuf, row_ptr, col, bl[L], maxPart + L * 256, abuf, N, (L > 0) ? 1 : 0);
    cur = abuf;
  }

  hipLaunchKernelGGL(k_pool, dim3(B), dim3(128), 0, stream, abuf, gstart, pooled, B);
  hipLaunchKernelGGL(k_gemm, dim3((B + 31) / 32, H / 128), dim3(256), 0, stream,
                     pooled, Wf1, bf1, o1, B, 128, H, 1);
  hipLaunchKernelGGL(k_gemm, dim3((B + 31) / 32, 1), dim3(256), 0, stream,
                     o1, Wf2, bf2, (float*)d_out, B, H, 128, 0);
}

// Round 3
// 657.475 us; speedup vs baseline: 1.4119x; 1.2563x over previous
//
#include <hip/hip_runtime.h>
#include <cstdint>
#include <cstddef>

#define NEG_SLOPE 0.2f

__device__ __forceinline__ unsigned enc_f(float f) {
  unsigned u = __float_as_uint(f);
  return (u & 0x80000000u) ? ~u : (u | 0x80000000u);
}
__device__ __forceinline__ float dec_f(unsigned u) {
  return (u & 0x80000000u) ? __uint_as_float(u ^ 0x80000000u) : __uint_as_float(~u);
}
__device__ __forceinline__ unsigned short f2bf(float f) {
  unsigned u = __float_as_uint(f);
  unsigned r = u + 0x7fffu + ((u >> 16) & 1u);
  return (unsigned short)(r >> 16);
}
#define BLO(u) __uint_as_float((u) << 16)
#define BHI(u) __uint_as_float((u) & 0xffff0000u)

// ---------------- CSR build ----------------
__global__ void k_init(int* counts, unsigned* maxPart, int N) {
  int n = blockIdx.x * blockDim.x + threadIdx.x;
  if (n < N) counts[n] = 1;  // self loop
  if (n < 768) maxPart[n] = 0u;
}

__global__ void k_count_rank(const int* __restrict__ dst, int E,
                             int* counts, int* __restrict__ rank) {
  int e = blockIdx.x * blockDim.x + threadIdx.x;
  if (e < E) rank[e] = atomicAdd(&counts[dst[e]], 1);
}

__global__ __launch_bounds__(1024) void k_scan1(const int* __restrict__ counts, int N,
                                                int* __restrict__ row_ptr, int* __restrict__ part) {
  __shared__ int tmp[1024];
  int t = threadIdx.x;
  int i = blockIdx.x * 1024 + t;
  int v = (i < N) ? counts[i] : 0;
  tmp[t] = v;
  __syncthreads();
  for (int off = 1; off < 1024; off <<= 1) {
    int u = (t >= off) ? tmp[t - off] : 0;
    __syncthreads();
    tmp[t] += u;
    __syncthreads();
  }
  if (i < N) row_ptr[i + 1] = tmp[t];
  if (t == 1023) part[blockIdx.x] = tmp[t];
}

__global__ void k_scan2(int* part, int nb, int* row_ptr) {
  if (threadIdx.x == 0 && blockIdx.x == 0) {
    int run = 0;
    for (int b = 0; b < nb; b++) { int v = part[b]; part[b] = run; run += v; }
    row_ptr[0] = 0;
  }
}

__global__ __launch_bounds__(1024) void k_scan3(int* __restrict__ row_ptr,
                                                const int* __restrict__ part, int N) {
  int i = blockIdx.x * 1024 + threadIdx.x;
  if (i < N) row_ptr[i + 1] += part[blockIdx.x];
}

__global__ void k_fill_self(const int* __restrict__ row_ptr, int* __restrict__ col, int N) {
  int n = blockIdx.x * blockDim.x + threadIdx.x;
  if (n < N) col[row_ptr[n]] = n;
}

__global__ void k_fill(const int* __restrict__ src, const int* __restrict__ dst,
                       const int* __restrict__ rank, int E,
                       const int* __restrict__ row_ptr, int* __restrict__ col) {
  int e = blockIdx.x * blockDim.x + threadIdx.x;
  if (e < E) col[row_ptr[dst[e]] + rank[e]] = src[e];
}

// ---------------- plain fp32 GEMM (MLP head): C = A@W + bias (+relu) ----------------
#define CK 64
__global__ __launch_bounds__(256) void k_gemm(const float* __restrict__ A,
                                              const float* __restrict__ W,
                                              const float* __restrict__ bias,
                                              float* __restrict__ C,
                                              int M, int K, int Nc, int relu) {
  __shared__ float As[32][CK + 4];
  __shared__ float Ws[CK][128];
  int t = threadIdx.x;
  int tx = t & 31;
  int ty = t >> 5;
  int rowbase = blockIdx.x * 32;
  int colbase = blockIdx.y * 128;
  float4 acc[4];
  acc[0] = acc[1] = acc[2] = acc[3] = make_float4(0.f, 0.f, 0.f, 0.f);

  for (int kb = 0; kb < K; kb += CK) {
    for (int idx = t * 4; idx < 32 * CK; idx += 256 * 4) {
      int r = idx / CK, kk = idx % CK;
      int gr = rowbase + r;
      float4 v = make_float4(0.f, 0.f, 0.f, 0.f);
      if (gr < M) v = *(const float4*)&A[(size_t)gr * K + kb + kk];
      *(float4*)&As[r][kk] = v;
    }
    for (int idx = t * 4; idx < CK * 128; idx += 256 * 4) {
      int kk = idx >> 7, cc = idx & 127;
      *(float4*)&Ws[kk][cc] = *(const float4*)&W[(size_t)(kb + kk) * Nc + colbase + cc];
    }
    __syncthreads();
#pragma unroll
    for (int kk = 0; kk < CK; kk++) {
      float4 w = *(float4*)&Ws[kk][tx * 4];
#pragma unroll
      for (int r = 0; r < 4; r++) {
        float a = As[ty + 8 * r][kk];
        acc[r].x += a * w.x; acc[r].y += a * w.y; acc[r].z += a * w.z; acc[r].w += a * w.w;
      }
    }
    __syncthreads();
  }

  float4 bv = make_float4(0.f, 0.f, 0.f, 0.f);
  if (bias) bv = *(const float4*)&bias[colbase + tx * 4];
#pragma unroll
  for (int r = 0; r < 4; r++) {
    int gr = rowbase + ty + 8 * r;
    if (gr < M) {
      float4 o = acc[r];
      o.x += bv.x; o.y += bv.y; o.z += bv.z; o.w += bv.w;
      if (relu) { o.x = fmaxf(o.x, 0.f); o.y = fmaxf(o.y, 0.f); o.z = fmaxf(o.z, 0.f); o.w = fmaxf(o.w, 0.f); }
      *(float4*)&C[(size_t)gr * Nc + colbase + tx * 4] = o;
    }
  }
}

// ---------------- layer GEMM fused: hb(bf16) = A@W ; s = h.a_src ; d = h.a_dst ; partial max(s) ----
// K == Nc == 128, gridDim.y == 1
__global__ __launch_bounds__(256) void k_gemm_fused(const float* __restrict__ A,
                                                    const float* __restrict__ W,
                                                    unsigned short* __restrict__ hb,
                                                    const float* __restrict__ asrc,
                                                    const float* __restrict__ adst,
                                                    float* __restrict__ sv, float* __restrict__ dv,
                                                    unsigned* __restrict__ maxSlot, int M) {
  __shared__ float As[32][CK + 4];
  __shared__ float Ws[CK][128];
  __shared__ float redmax[4];
  const int K = 128, Nc = 128;
  int t = threadIdx.x;
  int tx = t & 31;
  int ty = t >> 5;
  int rowbase = blockIdx.x * 32;
  float4 acc[4];
  acc[0] = acc[1] = acc[2] = acc[3] = make_float4(0.f, 0.f, 0.f, 0.f);

  for (int kb = 0; kb < K; kb += CK) {
    for (int idx = t * 4; idx < 32 * CK; idx += 256 * 4) {
      int r = idx / CK, kk = idx % CK;
      int gr = rowbase + r;
      float4 v = make_float4(0.f, 0.f, 0.f, 0.f);
      if (gr < M) v = *(const float4*)&A[(size_t)gr * K + kb + kk];
      *(float4*)&As[r][kk] = v;
    }
    for (int idx = t * 4; idx < CK * 128; idx += 256 * 4) {
      int kk = idx >> 7, cc = idx & 127;
      *(float4*)&Ws[kk][cc] = *(const float4*)&W[(size_t)(kb + kk) * Nc + cc];
    }
    __syncthreads();
#pragma unroll
    for (int kk = 0; kk < CK; kk++) {
      float4 w = *(float4*)&Ws[kk][tx * 4];
#pragma unroll
      for (int r = 0; r < 4; r++) {
        float a = As[ty + 8 * r][kk];
        acc[r].x += a * w.x; acc[r].y += a * w.y; acc[r].z += a * w.z; acc[r].w += a * w.w;
      }
    }
    __syncthreads();
  }

  // epilogue: bf16 h write + per-row s,d + block max(s)
  float4 av  = *(const float4*)&asrc[tx * 4];
  float4 adv = *(const float4*)&adst[tx * 4];
  float wmax = -1e30f;
#pragma unroll
  for (int r = 0; r < 4; r++) {
    int gr = rowbase + ty + 8 * r;
    float4 o = acc[r];
    float ps = o.x * av.x + o.y * av.y + o.z * av.z + o.w * av.w;
    float pd = o.x * adv.x + o.y * adv.y + o.z * adv.z + o.w * adv.w;
#pragma unroll
    for (int mask = 16; mask; mask >>= 1) {
      ps += __shfl_xor(ps, mask);
      pd += __shfl_xor(pd, mask);
    }
    if (gr < M) {
      ushort4 hv;
      hv.x = f2bf(o.x); hv.y = f2bf(o.y); hv.z = f2bf(o.z); hv.w = f2bf(o.w);
      *(ushort4*)&hb[(size_t)gr * 128 + tx * 4] = hv;
      if (tx == 0) { sv[gr] = ps; dv[gr] = pd; }
      wmax = fmaxf(wmax, ps);
    }
  }
#pragma unroll
  for (int mask = 32; mask; mask >>= 1) wmax = fmaxf(wmax, __shfl_xor(wmax, mask));
  if ((t & 63) == 0) redmax[t >> 6] = wmax;
  __syncthreads();
  if (t == 0) {
    float mx = fmaxf(fmaxf(redmax[0], redmax[1]), fmaxf(redmax[2], redmax[3]));
    atomicMax(&maxSlot[blockIdx.x & 255], enc_f(mx));
  }
}

// ---------------- segment-softmax aggregation: 1 wave/node, 4 round-robin groups of 16 lanes ------
__global__ __launch_bounds__(256) void k_agg(const unsigned short* __restrict__ hb,
                                             const float* __restrict__ sv,
                                             const float* __restrict__ dv,
                                             const int* __restrict__ row_ptr,
                                             const int* __restrict__ col,
                                             const float* __restrict__ bias,
                                             const unsigned* __restrict__ maxSlot,
                                             float* __restrict__ out, int N, int relu) {
  int wid = (int)((blockIdx.x * (size_t)blockDim.x + threadIdx.x) >> 6);
  int lane = threadIdx.x & 63;
  if (wid >= N) return;

  unsigned mp = max(max(maxSlot[lane], maxSlot[lane + 64]),
                    max(maxSlot[lane + 128], maxSlot[lane + 192]));
#pragma unroll
  for (int off = 32; off; off >>= 1) mp = max(mp, __shfl_xor(mp, off));
  float maxS = dec_f(mp);

  int beg = row_ptr[wid], end = row_ptr[wid + 1];
  float dn = dv[wid];
  float m = maxS + dn;
  m = (m > 0.f) ? m : NEG_SLOPE * m;  // upper bound on all incoming e (leaky_relu monotone)

  int g = lane >> 4, sub = lane & 15;
  const uint32_t* hbu = (const uint32_t*)hb;  // 64 uints per row
  float acc[8];
#pragma unroll
  for (int k = 0; k < 8; k++) acc[k] = 0.f;
  float dsum = 0.f;

  for (int j = beg + g; j < end; j += 4) {
    int sn = col[j];                       // same addr across 16 lanes -> broadcast
    float e = sv[sn] + dn;
    e = (e > 0.f) ? e : NEG_SLOPE * e;
    float wgt = __expf(e - m);
    dsum += wgt;
    uint4 hv = *(const uint4*)(hbu + (size_t)sn * 64 + sub * 4);
    acc[0] += wgt * BLO(hv.x); acc[1] += wgt * BHI(hv.x);
    acc[2] += wgt * BLO(hv.y); acc[3] += wgt * BHI(hv.y);
    acc[4] += wgt * BLO(hv.z); acc[5] += wgt * BHI(hv.z);
    acc[6] += wgt * BLO(hv.w); acc[7] += wgt * BHI(hv.w);
  }
  // combine the 4 groups (lane bits 4,5)
  dsum += __shfl_xor(dsum, 16);
  dsum += __shfl_xor(dsum, 32);
#pragma unroll
  for (int k = 0; k < 8; k++) {
    acc[k] += __shfl_xor(acc[k], 16);
    acc[k] += __shfl_xor(acc[k], 32);
  }
  if (lane < 16) {
    float inv = 1.f / dsum;
    float4 b0 = *(const float4*)&bias[sub * 8];
    float4 b1 = *(const float4*)&bias[sub * 8 + 4];
    float4 o0, o1;
    o0.x = acc[0] * inv + b0.x; o0.y = acc[1] * inv + b0.y;
    o0.z = acc[2] * inv + b0.z; o0.w = acc[3] * inv + b0.w;
    o1.x = acc[4] * inv + b1.x; o1.y = acc[5] * inv + b1.y;
    o1.z = acc[6] * inv + b1.z; o1.w = acc[7] * inv + b1.w;
    if (relu) {
      o0.x = fmaxf(o0.x, 0.f); o0.y = fmaxf(o0.y, 0.f); o0.z = fmaxf(o0.z, 0.f); o0.w = fmaxf(o0.w, 0.f);
      o1.x = fmaxf(o1.x, 0.f); o1.y = fmaxf(o1.y, 0.f); o1.z = fmaxf(o1.z, 0.f); o1.w = fmaxf(o1.w, 0.f);
    }
    float* op = &out[(size_t)wid * 128 + sub * 8];
    *(float4*)op = o0;
    *(float4*)(op + 4) = o1;
  }
}

// ---------------- batch boundaries (batch is sorted) ----------------
__global__ void k_bounds(const int* __restrict__ batch, int N, int B, int* __restrict__ gstart) {
  int n = blockIdx.x * blockDim.x + threadIdx.x;
  if (n >= N) return;
  int cur = batch[n];
  if (n == 0) {
    for (int g = 0; g <= cur; g++) gstart[g] = 0;
  } else {
    int prev = batch[n - 1];
    for (int g = prev + 1; g <= cur; g++) gstart[g] = n;
  }
  if (n == N - 1) {
    for (int g = cur + 1; g <= B; g++) gstart[g] = N;
  }
}

// ---------------- mean pool + relu ----------------
__global__ __launch_bounds__(128) void k_pool(const float* __restrict__ h,
                                              const int* __restrict__ gstart,
                                              float* __restrict__ pooled, int B) {
  int b = blockIdx.x, c = threadIdx.x;
  int s0 = gstart[b], s1 = gstart[b + 1];
  float acc = 0.f;
  for (int n = s0; n < s1; n++) acc += h[(size_t)n * 128 + c];
  int cnt = s1 - s0;
  float p = acc / (float)(cnt > 0 ? cnt : 1);
  pooled[b * 128 + c] = fmaxf(p, 0.f);
}

extern "C" void kernel_launch(void* const* d_in, const int* in_sizes, int n_in,
                              void* d_out, int out_size, void* d_ws, size_t ws_size,
                              hipStream_t stream) {
  const float* x     = (const float*)d_in[0];
  const int*   ei    = (const int*)d_in[1];
  const int*   batch = (const int*)d_in[3];
  const float* W1 = (const float*)d_in[4];
  const float* as1 = (const float*)d_in[5];
  const float* ad1 = (const float*)d_in[6];
  const float* b1 = (const float*)d_in[7];
  const float* W2 = (const float*)d_in[8];
  const float* as2 = (const float*)d_in[9];
  const float* ad2 = (const float*)d_in[10];
  const float* b2 = (const float*)d_in[11];
  const float* W3 = (const float*)d_in[12];
  const float* as3 = (const float*)d_in[13];
  const float* ad3 = (const float*)d_in[14];
  const float* b3 = (const float*)d_in[15];
  const float* Wf1 = (const float*)d_in[16];
  const float* bf1 = (const float*)d_in[17];
  const float* Wf2 = (const float*)d_in[18];
  const float* bf2 = (const float*)d_in[19];

  const int N = in_sizes[0] / 128;
  const int E = in_sizes[1] / 2;
  const int H = in_sizes[17];
  const int B = out_size / 128;

  char* base = (char*)d_ws;
  size_t off = 0;
  auto carve = [&](size_t bytes) -> void* {
    off = (off + 255) & ~(size_t)255;
    void* p = base + off;
    off += bytes;
    return p;
  };
  int* counts   = (int*)carve((size_t)N * 4);
  int* row_ptr  = (int*)carve((size_t)(N + 1) * 4);
  int* rank     = (int*)carve((size_t)E * 4);
  int* col      = (int*)carve((size_t)(E + N) * 4);
  int* part     = (int*)carve(1024 * 4);
  int* gstart   = (int*)carve((size_t)(B + 1) * 4);
  unsigned* maxPart = (unsigned*)carve(768 * 4);
  float* sbuf   = (float*)carve((size_t)N * 4);
  float* dbuf   = (float*)carve((size_t)N * 4);
  unsigned short* hb = (unsigned short*)carve((size_t)N * 128 * 2);
  float* abuf   = (float*)carve((size_t)N * 128 * 4);
  float* pooled = (float*)carve((size_t)B * 128 * 4);
  float* o1     = (float*)carve((size_t)B * H * 4);

  const int* srcp = ei;
  const int* dstp = ei + E;
  const int nb = (N + 1023) / 1024;

  hipLaunchKernelGGL(k_init, dim3((N + 255) / 256), dim3(256), 0, stream, counts, maxPart, N);
  hipLaunchKernelGGL(k_count_rank, dim3((E + 255) / 256), dim3(256), 0, stream, dstp, E, counts, rank);
  hipLaunchKernelGGL(k_scan1, dim3(nb), dim3(1024), 0, stream, counts, N, row_ptr, part);
  hipLaunchKernelGGL(k_scan2, dim3(1), dim3(64), 0, stream, part, nb, row_ptr);
  hipLaunchKernelGGL(k_scan3, dim3(nb), dim3(1024), 0, stream, row_ptr, part, N);
  hipLaunchKernelGGL(k_fill_self, dim3((N + 255) / 256), dim3(256), 0, stream, row_ptr, col, N);
  hipLaunchKernelGGL(k_fill, dim3((E + 255) / 256), dim3(256), 0, stream, srcp, dstp, rank, E, row_ptr, col);
  hipLaunchKernelGGL(k_bounds, dim3((N + 255) / 256), dim3(256), 0, stream, batch, N, B, gstart);

  const float* Wl[3] = {W1, W2, W3};
  const float* al[3] = {as1, as2, as3};
  const float* dl[3] = {ad1, ad2, ad3};
  const float* bl[3] = {b1, b2, b3};
  const float* cur = x;
  for (int L = 0; L < 3; L++) {
    hipLaunchKernelGGL(k_gemm_fused, dim3((N + 31) / 32), dim3(256), 0, stream,
                       cur, Wl[L], hb, al[L], dl[L], sbuf, dbuf, maxPart + L * 256, N);
    hipLaunchKernelGGL(k_agg, dim3((N + 3) / 4), dim3(256), 0, stream,
                       hb, sbuf, dbuf, row_ptr, col, bl[L], maxPart + L * 256, abuf, N, (L > 0) ? 1 : 0);
    cur = abuf;
  }

  hipLaunchKernelGGL(k_pool, dim3(B), dim3(128), 0, stream, abuf, gstart, pooled, B);
  hipLaunchKernelGGL(k_gemm, dim3((B + 31) / 32, H / 128), dim3(256), 0, stream,
                     pooled, Wf1, bf1, o1, B, 128, H, 1);
  hipLaunchKernelGGL(k_gemm, dim3((B + 31) / 32, 1), dim3(256), 0, stream,
                     o1, Wf2, bf2, (float*)d_out, B, H, 128, 0);
}

// Round 4
// 606.575 us; speedup vs baseline: 1.5304x; 1.0839x over previous
//
#include <hip/hip_runtime.h>
#include <cstdint>
#include <cstddef>

#define NEG_SLOPE 0.2f

__device__ __forceinline__ unsigned enc_f(float f) {
  unsigned u = __float_as_uint(f);
  return (u & 0x80000000u) ? ~u : (u | 0x80000000u);
}
__device__ __forceinline__ float dec_f(unsigned u) {
  return (u & 0x80000000u) ? __uint_as_float(u ^ 0x80000000u) : __uint_as_float(~u);
}
__device__ __forceinline__ unsigned short f2bf(float f) {
  unsigned u = __float_as_uint(f);
  unsigned r = u + 0x7fffu + ((u >> 16) & 1u);
  return (unsigned short)(r >> 16);
}
#define BLO(u) __uint_as_float((u) << 16)
#define BHI(u) __uint_as_float((u) & 0xffff0000u)

// ---------------- CSR build ----------------
__global__ void k_init(int* counts, unsigned* maxPart, int N) {
  int n = blockIdx.x * blockDim.x + threadIdx.x;
  if (n < N) counts[n] = 1;  // self loop
  if (n < 768) maxPart[n] = 0u;
}

__global__ void k_count_rank(const int* __restrict__ dst, int E,
                             int* counts, int* __restrict__ rank) {
  int e = blockIdx.x * blockDim.x + threadIdx.x;
  if (e < E) rank[e] = atomicAdd(&counts[dst[e]], 1);
}

__global__ __launch_bounds__(1024) void k_scan1(const int* __restrict__ counts, int N,
                                                int* __restrict__ row_ptr, int* __restrict__ part) {
  __shared__ int tmp[1024];
  int t = threadIdx.x;
  int i = blockIdx.x * 1024 + t;
  int v = (i < N) ? counts[i] : 0;
  tmp[t] = v;
  __syncthreads();
  for (int off = 1; off < 1024; off <<= 1) {
    int u = (t >= off) ? tmp[t - off] : 0;
    __syncthreads();
    tmp[t] += u;
    __syncthreads();
  }
  if (i < N) row_ptr[i + 1] = tmp[t];
  if (t == 1023) part[blockIdx.x] = tmp[t];
}

__global__ void k_scan2(int* part, int nb, int* row_ptr) {
  if (threadIdx.x == 0 && blockIdx.x == 0) {
    int run = 0;
    for (int b = 0; b < nb; b++) { int v = part[b]; part[b] = run; run += v; }
    row_ptr[0] = 0;
  }
}

__global__ __launch_bounds__(1024) void k_scan3(int* __restrict__ row_ptr,
                                                const int* __restrict__ part, int N) {
  int i = blockIdx.x * 1024 + threadIdx.x;
  if (i < N) row_ptr[i + 1] += part[blockIdx.x];
}

// self loops (first N threads) + edges, no atomics
__global__ void k_fill(const int* __restrict__ src, const int* __restrict__ dst,
                       const int* __restrict__ rank, int E, int N,
                       const int* __restrict__ row_ptr, int* __restrict__ col) {
  int i = blockIdx.x * blockDim.x + threadIdx.x;
  if (i < N) col[row_ptr[i]] = i;
  int e = i - N;
  if (e >= 0 && e < E) col[row_ptr[dst[e]] + rank[e]] = src[e];
}

#define CK 64
// ---------------- layer GEMM fused: hb(bf16) = A@W ; s = h.a_src ; d = h.a_dst ; partial max(s) ----
// K == Nc == 128
__global__ __launch_bounds__(256) void k_gemm_fused(const float* __restrict__ A,
                                                    const float* __restrict__ W,
                                                    unsigned short* __restrict__ hb,
                                                    const float* __restrict__ asrc,
                                                    const float* __restrict__ adst,
                                                    float* __restrict__ sv, float* __restrict__ dv,
                                                    unsigned* __restrict__ maxSlot, int M) {
  __shared__ float As[32][CK + 4];
  __shared__ float Ws[CK][128];
  __shared__ float redmax[4];
  const int K = 128, Nc = 128;
  int t = threadIdx.x;
  int tx = t & 31;
  int ty = t >> 5;
  int rowbase = blockIdx.x * 32;
  float4 acc[4];
  acc[0] = acc[1] = acc[2] = acc[3] = make_float4(0.f, 0.f, 0.f, 0.f);

  for (int kb = 0; kb < K; kb += CK) {
    for (int idx = t * 4; idx < 32 * CK; idx += 256 * 4) {
      int r = idx / CK, kk = idx % CK;
      int gr = rowbase + r;
      float4 v = make_float4(0.f, 0.f, 0.f, 0.f);
      if (gr < M) v = *(const float4*)&A[(size_t)gr * K + kb + kk];
      *(float4*)&As[r][kk] = v;
    }
    for (int idx = t * 4; idx < CK * 128; idx += 256 * 4) {
      int kk = idx >> 7, cc = idx & 127;
      *(float4*)&Ws[kk][cc] = *(const float4*)&W[(size_t)(kb + kk) * Nc + cc];
    }
    __syncthreads();
#pragma unroll
    for (int kk = 0; kk < CK; kk++) {
      float4 w = *(float4*)&Ws[kk][tx * 4];
#pragma unroll
      for (int r = 0; r < 4; r++) {
        float a = As[ty + 8 * r][kk];
        acc[r].x += a * w.x; acc[r].y += a * w.y; acc[r].z += a * w.z; acc[r].w += a * w.w;
      }
    }
    __syncthreads();
  }

  float4 av  = *(const float4*)&asrc[tx * 4];
  float4 adv = *(const float4*)&adst[tx * 4];
  float wmax = -1e30f;
#pragma unroll
  for (int r = 0; r < 4; r++) {
    int gr = rowbase + ty + 8 * r;
    float4 o = acc[r];
    float ps = o.x * av.x + o.y * av.y + o.z * av.z + o.w * av.w;
    float pd = o.x * adv.x + o.y * adv.y + o.z * adv.z + o.w * adv.w;
#pragma unroll
    for (int mask = 16; mask; mask >>= 1) {
      ps += __shfl_xor(ps, mask);
      pd += __shfl_xor(pd, mask);
    }
    if (gr < M) {
      ushort4 hv;
      hv.x = f2bf(o.x); hv.y = f2bf(o.y); hv.z = f2bf(o.z); hv.w = f2bf(o.w);
      *(ushort4*)&hb[(size_t)gr * 128 + tx * 4] = hv;
      if (tx == 0) { sv[gr] = ps; dv[gr] = pd; }
      wmax = fmaxf(wmax, ps);
    }
  }
#pragma unroll
  for (int mask = 32; mask; mask >>= 1) wmax = fmaxf(wmax, __shfl_xor(wmax, mask));
  if ((t & 63) == 0) redmax[t >> 6] = wmax;
  __syncthreads();
  if (t == 0) {
    float mx = fmaxf(fmaxf(redmax[0], redmax[1]), fmaxf(redmax[2], redmax[3]));
    atomicMax(&maxSlot[blockIdx.x & 255], enc_f(mx));
  }
}

// ---------------- segment-softmax aggregation: 1 wave/node, 4 round-robin groups of 16 lanes ------
__global__ __launch_bounds__(256) void k_agg(const unsigned short* __restrict__ hb,
                                             const float* __restrict__ sv,
                                             const float* __restrict__ dv,
                                             const int* __restrict__ row_ptr,
                                             const int* __restrict__ col,
                                             const float* __restrict__ bias,
                                             const unsigned* __restrict__ maxSlot,
                                             float* __restrict__ out, int N, int relu) {
  int wid = (int)((blockIdx.x * (size_t)blockDim.x + threadIdx.x) >> 6);
  int lane = threadIdx.x & 63;
  if (wid >= N) return;

  unsigned mp = max(max(maxSlot[lane], maxSlot[lane + 64]),
                    max(maxSlot[lane + 128], maxSlot[lane + 192]));
#pragma unroll
  for (int off = 32; off; off >>= 1) mp = max(mp, __shfl_xor(mp, off));
  float maxS = dec_f(mp);

  int beg = row_ptr[wid], end = row_ptr[wid + 1];
  float dn = dv[wid];
  float m = maxS + dn;
  m = (m > 0.f) ? m : NEG_SLOPE * m;  // upper bound on all incoming e (leaky_relu monotone)

  int g = lane >> 4, sub = lane & 15;
  const uint32_t* hbu = (const uint32_t*)hb;
  float acc[8];
#pragma unroll
  for (int k = 0; k < 8; k++) acc[k] = 0.f;
  float dsum = 0.f;

  for (int j = beg + g; j < end; j += 4) {
    int sn = col[j];
    float e = sv[sn] + dn;
    e = (e > 0.f) ? e : NEG_SLOPE * e;
    float wgt = __expf(e - m);
    dsum += wgt;
    uint4 hv = *(const uint4*)(hbu + (size_t)sn * 64 + sub * 4);
    acc[0] += wgt * BLO(hv.x); acc[1] += wgt * BHI(hv.x);
    acc[2] += wgt * BLO(hv.y); acc[3] += wgt * BHI(hv.y);
    acc[4] += wgt * BLO(hv.z); acc[5] += wgt * BHI(hv.z);
    acc[6] += wgt * BLO(hv.w); acc[7] += wgt * BHI(hv.w);
  }
  dsum += __shfl_xor(dsum, 16);
  dsum += __shfl_xor(dsum, 32);
#pragma unroll
  for (int k = 0; k < 8; k++) {
    acc[k] += __shfl_xor(acc[k], 16);
    acc[k] += __shfl_xor(acc[k], 32);
  }
  if (lane < 16) {
    float inv = 1.f / dsum;
    float4 b0 = *(const float4*)&bias[sub * 8];
    float4 b1 = *(const float4*)&bias[sub * 8 + 4];
    float4 o0, o1;
    o0.x = acc[0] * inv + b0.x; o0.y = acc[1] * inv + b0.y;
    o0.z = acc[2] * inv + b0.z; o0.w = acc[3] * inv + b0.w;
    o1.x = acc[4] * inv + b1.x; o1.y = acc[5] * inv + b1.y;
    o1.z = acc[6] * inv + b1.z; o1.w = acc[7] * inv + b1.w;
    if (relu) {
      o0.x = fmaxf(o0.x, 0.f); o0.y = fmaxf(o0.y, 0.f); o0.z = fmaxf(o0.z, 0.f); o0.w = fmaxf(o0.w, 0.f);
      o1.x = fmaxf(o1.x, 0.f); o1.y = fmaxf(o1.y, 0.f); o1.z = fmaxf(o1.z, 0.f); o1.w = fmaxf(o1.w, 0.f);
    }
    float* op = &out[(size_t)wid * 128 + sub * 8];
    *(float4*)op = o0;
    *(float4*)(op + 4) = o1;
  }
}

// ---------------- batch boundaries (batch is sorted) ----------------
__global__ void k_bounds(const int* __restrict__ batch, int N, int B, int* __restrict__ gstart) {
  int n = blockIdx.x * blockDim.x + threadIdx.x;
  if (n >= N) return;
  int cur = batch[n];
  if (n == 0) {
    for (int g = 0; g <= cur; g++) gstart[g] = 0;
  } else {
    int prev = batch[n - 1];
    for (int g = prev + 1; g <= cur; g++) gstart[g] = n;
  }
  if (n == N - 1) {
    for (int g = cur + 1; g <= B; g++) gstart[g] = N;
  }
}

// ---------------- mean pool + relu ----------------
__global__ __launch_bounds__(128) void k_pool(const float* __restrict__ h,
                                              const int* __restrict__ gstart,
                                              float* __restrict__ pooled, int B) {
  int b = blockIdx.x, c = threadIdx.x;
  int s0 = gstart[b], s1 = gstart[b + 1];
  float acc = 0.f;
  for (int n = s0; n < s1; n++) acc += h[(size_t)n * 128 + c];
  int cnt = s1 - s0;
  float p = acc / (float)(cnt > 0 ? cnt : 1);
  pooled[b * 128 + c] = fmaxf(p, 0.f);  // relu fused
}

// ---------------- fused MLP head: out = relu(pooled@Wf1+bf1)@Wf2+bf2, 4 graphs/block -------------
// pooled already relu'd. Wf1: 128x1024 row-major. Wf2: 1024x128 row-major.
__global__ __launch_bounds__(256) void k_mlp(const float* __restrict__ pooled,
                                             const float* __restrict__ Wf1,
                                             const float* __restrict__ bf1,
                                             const float* __restrict__ Wf2,
                                             const float* __restrict__ bf2,
                                             float* __restrict__ out, int B) {
  __shared__ float P[4][128];
  __shared__ float H1[4][1024];
  __shared__ float R[4][128];
  int t = threadIdx.x;
  int g0 = blockIdx.x * 4;

  for (int i = t; i < 4 * 128; i += 256) {
    int gi = i >> 7, c = i & 127;
    P[gi][c] = (g0 + gi < B) ? pooled[(size_t)(g0 + gi) * 128 + c] : 0.f;
  }
  __syncthreads();

  // phase 1: H1[g][c] = relu(sum_k P[g][k] * Wf1[k][c] + bf1[c]); thread t -> cols t, t+256, ...
#pragma unroll
  for (int cb = 0; cb < 4; cb++) {
    int c = cb * 256 + t;
    float a0 = 0.f, a1 = 0.f, a2 = 0.f, a3 = 0.f;
    for (int k = 0; k < 128; k++) {
      float w = Wf1[(size_t)k * 1024 + c];
      a0 += P[0][k] * w; a1 += P[1][k] * w; a2 += P[2][k] * w; a3 += P[3][k] * w;
    }
    float b = bf1[c];
    H1[0][c] = fmaxf(a0 + b, 0.f);
    H1[1][c] = fmaxf(a1 + b, 0.f);
    H1[2][c] = fmaxf(a2 + b, 0.f);
    H1[3][c] = fmaxf(a3 + b, 0.f);
  }
  __syncthreads();

  // phase 2: out[g][c] = sum_k H1[g][k] * Wf2[k][c] + bf2[c]; 2 threads per col (K halves)
  int c = t & 127, hh = t >> 7;
  float a0 = 0.f, a1 = 0.f, a2 = 0.f, a3 = 0.f;
  int k0 = hh * 512;
  for (int k = k0; k < k0 + 512; k++) {
    float w = Wf2[(size_t)k * 128 + c];
    a0 += H1[0][k] * w; a1 += H1[1][k] * w; a2 += H1[2][k] * w; a3 += H1[3][k] * w;
  }
  if (hh == 1) { R[0][c] = a0; R[1][c] = a1; R[2][c] = a2; R[3][c] = a3; }
  __syncthreads();
  if (hh == 0) {
    float b = bf2[c];
    float o0 = a0 + R[0][c] + b;
    float o1 = a1 + R[1][c] + b;
    float o2 = a2 + R[2][c] + b;
    float o3 = a3 + R[3][c] + b;
    if (g0 + 0 < B) out[(size_t)(g0 + 0) * 128 + c] = o0;
    if (g0 + 1 < B) out[(size_t)(g0 + 1) * 128 + c] = o1;
    if (g0 + 2 < B) out[(size_t)(g0 + 2) * 128 + c] = o2;
    if (g0 + 3 < B) out[(size_t)(g0 + 3) * 128 + c] = o3;
  }
}

extern "C" void kernel_launch(void* const* d_in, const int* in_sizes, int n_in,
                              void* d_out, int out_size, void* d_ws, size_t ws_size,
                              hipStream_t stream) {
  const float* x     = (const float*)d_in[0];
  const int*   ei    = (const int*)d_in[1];
  const int*   batch = (const int*)d_in[3];
  const float* W1 = (const float*)d_in[4];
  const float* as1 = (const float*)d_in[5];
  const float* ad1 = (const float*)d_in[6];
  const float* b1 = (const float*)d_in[7];
  const float* W2 = (const float*)d_in[8];
  const float* as2 = (const float*)d_in[9];
  const float* ad2 = (const float*)d_in[10];
  const float* b2 = (const float*)d_in[11];
  const float* W3 = (const float*)d_in[12];
  const float* as3 = (const float*)d_in[13];
  const float* ad3 = (const float*)d_in[14];
  const float* b3 = (const float*)d_in[15];
  const float* Wf1 = (const float*)d_in[16];
  const float* bf1 = (const float*)d_in[17];
  const float* Wf2 = (const float*)d_in[18];
  const float* bf2 = (const float*)d_in[19];

  const int N = in_sizes[0] / 128;
  const int E = in_sizes[1] / 2;
  const int B = out_size / 128;

  char* base = (char*)d_ws;
  size_t off = 0;
  auto carve = [&](size_t bytes) -> void* {
    off = (off + 255) & ~(size_t)255;
    void* p = base + off;
    off += bytes;
    return p;
  };
  int* counts   = (int*)carve((size_t)N * 4);
  int* row_ptr  = (int*)carve((size_t)(N + 1) * 4);
  int* rank     = (int*)carve((size_t)E * 4);
  int* col      = (int*)carve((size_t)(E + N) * 4);
  int* part     = (int*)carve(1024 * 4);
  int* gstart   = (int*)carve((size_t)(B + 1) * 4);
  unsigned* maxPart = (unsigned*)carve(768 * 4);
  float* sbuf   = (float*)carve((size_t)N * 4);
  float* dbuf   = (float*)carve((size_t)N * 4);
  unsigned short* hb = (unsigned short*)carve((size_t)N * 128 * 2);
  float* abuf   = (float*)carve((size_t)N * 128 * 4);
  float* pooled = (float*)carve((size_t)B * 128 * 4);

  const int* srcp = ei;
  const int* dstp = ei + E;
  const int nb = (N + 1023) / 1024;

  hipLaunchKernelGGL(k_init, dim3((N + 255) / 256), dim3(256), 0, stream, counts, maxPart, N);
  hipLaunchKernelGGL(k_count_rank, dim3((E + 255) / 256), dim3(256), 0, stream, dstp, E, counts, rank);
  hipLaunchKernelGGL(k_scan1, dim3(nb), dim3(1024), 0, stream, counts, N, row_ptr, part);
  hipLaunchKernelGGL(k_scan2, dim3(1), dim3(64), 0, stream, part, nb, row_ptr);
  hipLaunchKernelGGL(k_scan3, dim3(nb), dim3(1024), 0, stream, row_ptr, part, N);
  hipLaunchKernelGGL(k_fill, dim3((E + N + 255) / 256), dim3(256), 0, stream,
                     srcp, dstp, rank, E, N, row_ptr, col);
  hipLaunchKernelGGL(k_bounds, dim3((N + 255) / 256), dim3(256), 0, stream, batch, N, B, gstart);

  const float* Wl[3] = {W1, W2, W3};
  const float* al[3] = {as1, as2, as3};
  const float* dl[3] = {ad1, ad2, ad3};
  const float* bl[3] = {b1, b2, b3};
  const float* cur = x;
  for (int L = 0; L < 3; L++) {
    hipLaunchKernelGGL(k_gemm_fused, dim3((N + 31) / 32), dim3(256), 0, stream,
                       cur, Wl[L], hb, al[L], dl[L], sbuf, dbuf, maxPart + L * 256, N);
    hipLaunchKernelGGL(k_agg, dim3((N + 3) / 4), dim3(256), 0, stream,
                       hb, sbuf, dbuf, row_ptr, col, bl[L], maxPart + L * 256, abuf, N, (L > 0) ? 1 : 0);
    cur = abuf;
  }

  hipLaunchKernelGGL(k_pool, dim3(B), dim3(128), 0, stream, abuf, gstart, pooled, B);
  hipLaunchKernelGGL(k_mlp, dim3((B + 3) / 4), dim3(256), 0, stream,
                     pooled, Wf1, bf1, Wf2, bf2, (float*)d_out, B);
}

// Round 5
// 580.568 us; speedup vs baseline: 1.5990x; 1.0448x over previous
//
#include <hip/hip_runtime.h>
#include <cstdint>
#include <cstddef>

#define NEG_SLOPE 0.2f

typedef _Float16 f16x8 __attribute__((ext_vector_type(8)));
typedef float f32x4v __attribute__((ext_vector_type(4)));

__device__ __forceinline__ unsigned enc_f(float f) {
  unsigned u = __float_as_uint(f);
  return (u & 0x80000000u) ? ~u : (u | 0x80000000u);
}
__device__ __forceinline__ float dec_f(unsigned u) {
  return (u & 0x80000000u) ? __uint_as_float(u ^ 0x80000000u) : __uint_as_float(~u);
}
__device__ __forceinline__ unsigned short f2bf(float f) {
  unsigned u = __float_as_uint(f);
  unsigned r = u + 0x7fffu + ((u >> 16) & 1u);
  return (unsigned short)(r >> 16);
}
#define BLO(u) __uint_as_float((u) << 16)
#define BHI(u) __uint_as_float((u) & 0xffff0000u)

// ---------------- CSR build ----------------
__global__ void k_init(int* counts, unsigned* maxPart, int N) {
  int n = blockIdx.x * blockDim.x + threadIdx.x;
  if (n < N) counts[n] = 1;  // self loop
  if (n < 768) maxPart[n] = 0u;
}

// 4 edges/thread: 4 independent returning atomics in flight per lane
__global__ void k_count_rank(const int* __restrict__ dst, int E,
                             int* counts, int* __restrict__ rank) {
  int i = (blockIdx.x * blockDim.x + threadIdx.x) * 4;
  if (i + 3 < E) {
    int4 d = *(const int4*)&dst[i];
    int4 r;
    r.x = atomicAdd(&counts[d.x], 1);
    r.y = atomicAdd(&counts[d.y], 1);
    r.z = atomicAdd(&counts[d.z], 1);
    r.w = atomicAdd(&counts[d.w], 1);
    *(int4*)&rank[i] = r;
  } else {
    for (int e = i; e < E; e++) rank[e] = atomicAdd(&counts[dst[e]], 1);
  }
}
__global__ void k_count_rank_s(const int* __restrict__ dst, int E,
                               int* counts, int* __restrict__ rank) {
  int e = blockIdx.x * blockDim.x + threadIdx.x;
  if (e < E) rank[e] = atomicAdd(&counts[dst[e]], 1);
}

__global__ __launch_bounds__(1024) void k_scan1(const int* __restrict__ counts, int N,
                                                int* __restrict__ row_ptr, int* __restrict__ part) {
  __shared__ int tmp[1024];
  int t = threadIdx.x;
  int i = blockIdx.x * 1024 + t;
  int v = (i < N) ? counts[i] : 0;
  tmp[t] = v;
  __syncthreads();
  for (int off = 1; off < 1024; off <<= 1) {
    int u = (t >= off) ? tmp[t - off] : 0;
    __syncthreads();
    tmp[t] += u;
    __syncthreads();
  }
  if (i < N) row_ptr[i + 1] = tmp[t];
  if (t == 1023) part[blockIdx.x] = tmp[t];
}

__global__ void k_scan2(int* part, int nb, int* row_ptr) {
  if (threadIdx.x == 0 && blockIdx.x == 0) {
    int run = 0;
    for (int b = 0; b < nb; b++) { int v = part[b]; part[b] = run; run += v; }
    row_ptr[0] = 0;
  }
}

__global__ __launch_bounds__(1024) void k_scan3(int* __restrict__ row_ptr,
                                                const int* __restrict__ part, int N) {
  int i = blockIdx.x * 1024 + threadIdx.x;
  if (i < N) row_ptr[i + 1] += part[blockIdx.x];
}

__global__ void k_fill_self(const int* __restrict__ row_ptr, int* __restrict__ col, int N) {
  int n = blockIdx.x * blockDim.x + threadIdx.x;
  if (n < N) col[row_ptr[n]] = n;
}

__global__ void k_fill(const int* __restrict__ src, const int* __restrict__ dst,
                       const int* __restrict__ rank, int E,
                       const int* __restrict__ row_ptr, int* __restrict__ col) {
  int i = (blockIdx.x * blockDim.x + threadIdx.x) * 4;
  if (i + 3 < E) {
    int4 s = *(const int4*)&src[i];
    int4 d = *(const int4*)&dst[i];
    int4 r = *(const int4*)&rank[i];
    col[row_ptr[d.x] + r.x] = s.x;
    col[row_ptr[d.y] + r.y] = s.y;
    col[row_ptr[d.z] + r.z] = s.z;
    col[row_ptr[d.w] + r.w] = s.w;
  } else {
    for (int e = i; e < E; e++) col[row_ptr[dst[e]] + rank[e]] = src[e];
  }
}
__global__ void k_fill_s(const int* __restrict__ src, const int* __restrict__ dst,
                         const int* __restrict__ rank, int E,
                         const int* __restrict__ row_ptr, int* __restrict__ col) {
  int e = blockIdx.x * blockDim.x + threadIdx.x;
  if (e < E) col[row_ptr[dst[e]] + rank[e]] = src[e];
}

// ---------------- layer GEMM fused (fp16 MFMA): hb(bf16)=A@W ; s,d ; partial max(s) -------------
// A: Mx128 fp32, W: 128x128 fp32. 64-row M-tile per block, 4 waves, 16x16x32 f16 MFMA.
#define AST 136   // f16 elems per Ah row (pad for 16B alignment + bank spread)
#define WST 136   // f16 elems per Wt row
#define HST 132   // f32 elems per hS row
__global__ __launch_bounds__(256) void k_gemm_fused(const float* __restrict__ A,
                                                    const float* __restrict__ W,
                                                    unsigned short* __restrict__ hb,
                                                    const float* __restrict__ asrc,
                                                    const float* __restrict__ adst,
                                                    float* __restrict__ sv, float* __restrict__ dv,
                                                    unsigned* __restrict__ maxSlot, int M) {
  __shared__ __align__(16) char smem[64 * AST * 2 + 128 * WST * 2];
  _Float16* Ah = (_Float16*)smem;                       // [64][AST]
  _Float16* Wt = (_Float16*)(smem + 64 * AST * 2);      // [128][WST]  (transposed W: [n][k])
  float*    hS = (float*)(smem + 64 * AST * 2);         // [64][HST]   aliases Wt after mfma
  __shared__ float redmax[4];
  int t = threadIdx.x;
  int rowbase = blockIdx.x * 64;

  // stage A -> f16 (row-major, K contiguous)
  for (int i = t; i < 64 * 32; i += 256) {
    int r = i >> 5, c4 = (i & 31) << 2;
    int gr = rowbase + r;
    float4 v = make_float4(0.f, 0.f, 0.f, 0.f);
    if (gr < M) v = *(const float4*)&A[(size_t)gr * 128 + c4];
    _Float16 tmp[4] = {(_Float16)v.x, (_Float16)v.y, (_Float16)v.z, (_Float16)v.w};
    *(short4*)&Ah[r * AST + c4] = *(short4*)tmp;
  }
  // stage W transposed -> f16 ([n][k], K contiguous)
  for (int i = t; i < 128 * 32; i += 256) {
    int r = i >> 5, c4 = (i & 31) << 2;   // r = k, c4 = n base
    float4 v = *(const float4*)&W[(size_t)r * 128 + c4];
    Wt[(c4 + 0) * WST + r] = (_Float16)v.x;
    Wt[(c4 + 1) * WST + r] = (_Float16)v.y;
    Wt[(c4 + 2) * WST + r] = (_Float16)v.z;
    Wt[(c4 + 3) * WST + r] = (_Float16)v.w;
  }
  __syncthreads();

  int wave = t >> 6, lane = t & 63, quad = lane >> 4, l15 = lane & 15;
  f32x4v acc[4][2];
#pragma unroll
  for (int mt = 0; mt < 4; mt++)
#pragma unroll
    for (int nt = 0; nt < 2; nt++) {
      acc[mt][nt][0] = 0.f; acc[mt][nt][1] = 0.f; acc[mt][nt][2] = 0.f; acc[mt][nt][3] = 0.f;
    }

#pragma unroll
  for (int s = 0; s < 4; s++) {
    int k0 = (s << 5) + (quad << 3);
    f16x8 af[4], bf[2];
#pragma unroll
    for (int mt = 0; mt < 4; mt++)
      af[mt] = *(f16x8*)&Ah[(mt * 16 + l15) * AST + k0];
#pragma unroll
    for (int nt = 0; nt < 2; nt++)
      bf[nt] = *(f16x8*)&Wt[(wave * 32 + nt * 16 + l15) * WST + k0];
#pragma unroll
    for (int mt = 0; mt < 4; mt++)
#pragma unroll
      for (int nt = 0; nt < 2; nt++)
        acc[mt][nt] = __builtin_amdgcn_mfma_f32_16x16x32_f16(af[mt], bf[nt], acc[mt][nt], 0, 0, 0);
  }
  __syncthreads();  // everyone done reading Wt

  // acc (C-layout: n=lane&15, m=quad*4+reg) -> hS[64][HST]
#pragma unroll
  for (int mt = 0; mt < 4; mt++)
#pragma unroll
    for (int nt = 0; nt < 2; nt++)
#pragma unroll
      for (int rr = 0; rr < 4; rr++)
        hS[(mt * 16 + quad * 4 + rr) * HST + wave * 32 + nt * 16 + l15] = acc[mt][nt][rr];
  __syncthreads();

  // epilogue: bf16 hb store + s,d per row + block max(s)
  int tx = t & 31, ty = t >> 5;
  float4 av  = *(const float4*)&asrc[tx * 4];
  float4 adv = *(const float4*)&adst[tx * 4];
  float wmax = -1e30f;
#pragma unroll
  for (int r8 = 0; r8 < 8; r8++) {
    int row = r8 * 8 + ty;
    int gr = rowbase + row;
    float4 hv = *(float4*)&hS[row * HST + tx * 4];
    float ps = hv.x * av.x + hv.y * av.y + hv.z * av.z + hv.w * av.w;
    float pd = hv.x * adv.x + hv.y * adv.y + hv.z * adv.z + hv.w * adv.w;
#pragma unroll
    for (int mask = 16; mask; mask >>= 1) {
      ps += __shfl_xor(ps, mask);
      pd += __shfl_xor(pd, mask);
    }
    if (gr < M) {
      ushort4 hq;
      hq.x = f2bf(hv.x); hq.y = f2bf(hv.y); hq.z = f2bf(hv.z); hq.w = f2bf(hv.w);
      *(ushort4*)&hb[(size_t)gr * 128 + tx * 4] = hq;
      if (tx == 0) { sv[gr] = ps; dv[gr] = pd; wmax = fmaxf(wmax, ps); }
    }
  }
#pragma unroll
  for (int mask = 32; mask; mask >>= 1) wmax = fmaxf(wmax, __shfl_xor(wmax, mask));
  if ((t & 63) == 0) redmax[t >> 6] = wmax;
  __syncthreads();
  if (t == 0) {
    float mx = fmaxf(fmaxf(redmax[0], redmax[1]), fmaxf(redmax[2], redmax[3]));
    atomicMax(&maxSlot[blockIdx.x & 255], enc_f(mx));
  }
}

// ---------------- segment-softmax aggregation: 1 wave/node, 4 round-robin groups of 16 lanes ------
__global__ __launch_bounds__(256) void k_agg(const unsigned short* __restrict__ hb,
                                             const float* __restrict__ sv,
                                             const float* __restrict__ dv,
                                             const int* __restrict__ row_ptr,
                                             const int* __restrict__ col,
                                             const float* __restrict__ bias,
                                             const unsigned* __restrict__ maxSlot,
                                             float* __restrict__ out, int N, int relu) {
  int wid = (int)((blockIdx.x * (size_t)blockDim.x + threadIdx.x) >> 6);
  int lane = threadIdx.x & 63;
  if (wid >= N) return;

  unsigned mp = max(max(maxSlot[lane], maxSlot[lane + 64]),
                    max(maxSlot[lane + 128], maxSlot[lane + 192]));
#pragma unroll
  for (int off = 32; off; off >>= 1) mp = max(mp, __shfl_xor(mp, off));
  float maxS = dec_f(mp);

  int beg = row_ptr[wid], end = row_ptr[wid + 1];
  float dn = dv[wid];
  float m = maxS + dn;
  m = (m > 0.f) ? m : NEG_SLOPE * m;  // upper bound on all incoming e (leaky_relu monotone)

  int g = lane >> 4, sub = lane & 15;
  const uint32_t* hbu = (const uint32_t*)hb;
  float acc[8];
#pragma unroll
  for (int k = 0; k < 8; k++) acc[k] = 0.f;
  float dsum = 0.f;

  for (int j = beg + g; j < end; j += 4) {
    int sn = col[j];
    float e = sv[sn] + dn;
    e = (e > 0.f) ? e : NEG_SLOPE * e;
    float wgt = __expf(e - m);
    dsum += wgt;
    uint4 hv = *(const uint4*)(hbu + (size_t)sn * 64 + sub * 4);
    acc[0] += wgt * BLO(hv.x); acc[1] += wgt * BHI(hv.x);
    acc[2] += wgt * BLO(hv.y); acc[3] += wgt * BHI(hv.y);
    acc[4] += wgt * BLO(hv.z); acc[5] += wgt * BHI(hv.z);
    acc[6] += wgt * BLO(hv.w); acc[7] += wgt * BHI(hv.w);
  }
  dsum += __shfl_xor(dsum, 16);
  dsum += __shfl_xor(dsum, 32);
#pragma unroll
  for (int k = 0; k < 8; k++) {
    acc[k] += __shfl_xor(acc[k], 16);
    acc[k] += __shfl_xor(acc[k], 32);
  }
  if (lane < 16) {
    float inv = 1.f / dsum;
    float4 b0 = *(const float4*)&bias[sub * 8];
    float4 b1 = *(const float4*)&bias[sub * 8 + 4];
    float4 o0, o1;
    o0.x = acc[0] * inv + b0.x; o0.y = acc[1] * inv + b0.y;
    o0.z = acc[2] * inv + b0.z; o0.w = acc[3] * inv + b0.w;
    o1.x = acc[4] * inv + b1.x; o1.y = acc[5] * inv + b1.y;
    o1.z = acc[6] * inv + b1.z; o1.w = acc[7] * inv + b1.w;
    if (relu) {
      o0.x = fmaxf(o0.x, 0.f); o0.y = fmaxf(o0.y, 0.f); o0.z = fmaxf(o0.z, 0.f); o0.w = fmaxf(o0.w, 0.f);
      o1.x = fmaxf(o1.x, 0.f); o1.y = fmaxf(o1.y, 0.f); o1.z = fmaxf(o1.z, 0.f); o1.w = fmaxf(o1.w, 0.f);
    }
    float* op = &out[(size_t)wid * 128 + sub * 8];
    *(float4*)op = o0;
    *(float4*)(op + 4) = o1;
  }
}

// ---------------- batch boundaries (batch is sorted) ----------------
__global__ void k_bounds(const int* __restrict__ batch, int N, int B, int* __restrict__ gstart) {
  int n = blockIdx.x * blockDim.x + threadIdx.x;
  if (n >= N) return;
  int cur = batch[n];
  if (n == 0) {
    for (int g = 0; g <= cur; g++) gstart[g] = 0;
  } else {
    int prev = batch[n - 1];
    for (int g = prev + 1; g <= cur; g++) gstart[g] = n;
  }
  if (n == N - 1) {
    for (int g = cur + 1; g <= B; g++) gstart[g] = N;
  }
}

// ---------------- mean pool + relu ----------------
__global__ __launch_bounds__(128) void k_pool(const float* __restrict__ h,
                                              const int* __restrict__ gstart,
                                              float* __restrict__ pooled, int B) {
  int b = blockIdx.x, c = threadIdx.x;
  int s0 = gstart[b], s1 = gstart[b + 1];
  float acc = 0.f;
  for (int n = s0; n < s1; n++) acc += h[(size_t)n * 128 + c];
  int cnt = s1 - s0;
  float p = acc / (float)(cnt > 0 ? cnt : 1);
  pooled[b * 128 + c] = fmaxf(p, 0.f);  // relu fused
}

// ---------------- fused MLP head ----------------
__global__ __launch_bounds__(256) void k_mlp(const float* __restrict__ pooled,
                                             const float* __restrict__ Wf1,
                                             const float* __restrict__ bf1,
                                             const float* __restrict__ Wf2,
                                             const float* __restrict__ bf2,
                                             float* __restrict__ out, int B) {
  __shared__ float P[4][128];
  __shared__ float H1[4][1024];
  __shared__ float R[4][128];
  int t = threadIdx.x;
  int g0 = blockIdx.x * 4;

  for (int i = t; i < 4 * 128; i += 256) {
    int gi = i >> 7, c = i & 127;
    P[gi][c] = (g0 + gi < B) ? pooled[(size_t)(g0 + gi) * 128 + c] : 0.f;
  }
  __syncthreads();

#pragma unroll
  for (int cb = 0; cb < 4; cb++) {
    int c = cb * 256 + t;
    float a0 = 0.f, a1 = 0.f, a2 = 0.f, a3 = 0.f;
    for (int k = 0; k < 128; k++) {
      float w = Wf1[(size_t)k * 1024 + c];
      a0 += P[0][k] * w; a1 += P[1][k] * w; a2 += P[2][k] * w; a3 += P[3][k] * w;
    }
    float b = bf1[c];
    H1[0][c] = fmaxf(a0 + b, 0.f);
    H1[1][c] = fmaxf(a1 + b, 0.f);
    H1[2][c] = fmaxf(a2 + b, 0.f);
    H1[3][c] = fmaxf(a3 + b, 0.f);
  }
  __syncthreads();

  int c = t & 127, hh = t >> 7;
  float a0 = 0.f, a1 = 0.f, a2 = 0.f, a3 = 0.f;
  int k0 = hh * 512;
  for (int k = k0; k < k0 + 512; k++) {
    float w = Wf2[(size_t)k * 128 + c];
    a0 += H1[0][k] * w; a1 += H1[1][k] * w; a2 += H1[2][k] * w; a3 += H1[3][k] * w;
  }
  if (hh == 1) { R[0][c] = a0; R[1][c] = a1; R[2][c] = a2; R[3][c] = a3; }
  __syncthreads();
  if (hh == 0) {
    float b = bf2[c];
    float o0 = a0 + R[0][c] + b;
    float o1 = a1 + R[1][c] + b;
    float o2 = a2 + R[2][c] + b;
    float o3 = a3 + R[3][c] + b;
    if (g0 + 0 < B) out[(size_t)(g0 + 0) * 128 + c] = o0;
    if (g0 + 1 < B) out[(size_t)(g0 + 1) * 128 + c] = o1;
    if (g0 + 2 < B) out[(size_t)(g0 + 2) * 128 + c] = o2;
    if (g0 + 3 < B) out[(size_t)(g0 + 3) * 128 + c] = o3;
  }
}

extern "C" void kernel_launch(void* const* d_in, const int* in_sizes, int n_in,
                              void* d_out, int out_size, void* d_ws, size_t ws_size,
                              hipStream_t stream) {
  const float* x     = (const float*)d_in[0];
  const int*   ei    = (const int*)d_in[1];
  const int*   batch = (const int*)d_in[3];
  const float* W1 = (const float*)d_in[4];
  const float* as1 = (const float*)d_in[5];
  const float* ad1 = (const float*)d_in[6];
  const float* b1 = (const float*)d_in[7];
  const float* W2 = (const float*)d_in[8];
  const float* as2 = (const float*)d_in[9];
  const float* ad2 = (const float*)d_in[10];
  const float* b2 = (const float*)d_in[11];
  const float* W3 = (const float*)d_in[12];
  const float* as3 = (const float*)d_in[13];
  const float* ad3 = (const float*)d_in[14];
  const float* b3 = (const float*)d_in[15];
  const float* Wf1 = (const float*)d_in[16];
  const float* bf1 = (const float*)d_in[17];
  const float* Wf2 = (const float*)d_in[18];
  const float* bf2 = (const float*)d_in[19];

  const int N = in_sizes[0] / 128;
  const int E = in_sizes[1] / 2;
  const int B = out_size / 128;

  char* base = (char*)d_ws;
  size_t off = 0;
  auto carve = [&](size_t bytes) -> void* {
    off = (off + 255) & ~(size_t)255;
    void* p = base + off;
    off += bytes;
    return p;
  };
  int* counts   = (int*)carve((size_t)N * 4);
  int* row_ptr  = (int*)carve((size_t)(N + 1) * 4);
  int* rank     = (int*)carve((size_t)E * 4);
  int* col      = (int*)carve((size_t)(E + N) * 4);
  int* part     = (int*)carve(1024 * 4);
  int* gstart   = (int*)carve((size_t)(B + 1) * 4);
  unsigned* maxPart = (unsigned*)carve(768 * 4);
  float* sbuf   = (float*)carve((size_t)N * 4);
  float* dbuf   = (float*)carve((size_t)N * 4);
  unsigned short* hb = (unsigned short*)carve((size_t)N * 128 * 2);
  float* abuf   = (float*)carve((size_t)N * 128 * 4);
  float* pooled = (float*)carve((size_t)B * 128 * 4);

  const int* srcp = ei;
  const int* dstp = ei + E;
  const int nb = (N + 1023) / 1024;

  hipLaunchKernelGGL(k_init, dim3((N + 255) / 256), dim3(256), 0, stream, counts, maxPart, N);
  if ((E & 3) == 0) {
    int nq = E / 4;
    hipLaunchKernelGGL(k_count_rank, dim3((nq + 255) / 256), dim3(256), 0, stream, dstp, E, counts, rank);
  } else {
    hipLaunchKernelGGL(k_count_rank_s, dim3((E + 255) / 256), dim3(256), 0, stream, dstp, E, counts, rank);
  }
  hipLaunchKernelGGL(k_scan1, dim3(nb), dim3(1024), 0, stream, counts, N, row_ptr, part);
  hipLaunchKernelGGL(k_scan2, dim3(1), dim3(64), 0, stream, part, nb, row_ptr);
  hipLaunchKernelGGL(k_scan3, dim3(nb), dim3(1024), 0, stream, row_ptr, part, N);
  hipLaunchKernelGGL(k_fill_self, dim3((N + 255) / 256), dim3(256), 0, stream, row_ptr, col, N);
  if ((E & 3) == 0) {
    int nq = E / 4;
    hipLaunchKernelGGL(k_fill, dim3((nq + 255) / 256), dim3(256), 0, stream, srcp, dstp, rank, E, row_ptr, col);
  } else {
    hipLaunchKernelGGL(k_fill_s, dim3((E + 255) / 256), dim3(256), 0, stream, srcp, dstp, rank, E, row_ptr, col);
  }
  hipLaunchKernelGGL(k_bounds, dim3((N + 255) / 256), dim3(256), 0, stream, batch, N, B, gstart);

  const float* Wl[3] = {W1, W2, W3};
  const float* al[3] = {as1, as2, as3};
  const float* dl[3] = {ad1, ad2, ad3};
  const float* bl[3] = {b1, b2, b3};
  const float* cur = x;
  for (int L = 0; L < 3; L++) {
    hipLaunchKernelGGL(k_gemm_fused, dim3((N + 63) / 64), dim3(256), 0, stream,
                       cur, Wl[L], hb, al[L], dl[L], sbuf, dbuf, maxPart + L * 256, N);
    hipLaunchKernelGGL(k_agg, dim3((N + 3) / 4), dim3(256), 0, stream,
                       hb, sbuf, dbuf, row_ptr, col, bl[L], maxPart + L * 256, abuf, N, (L > 0) ? 1 : 0);
    cur = abuf;
  }

  hipLaunchKernelGGL(k_pool, dim3(B), dim3(128), 0, stream, abuf, gstart, pooled, B);
  hipLaunchKernelGGL(k_mlp, dim3((B + 3) / 4), dim3(256), 0, stream,
                     pooled, Wf1, bf1, Wf2, bf2, (float*)d_out, B);
}

// Round 6
// 555.085 us; speedup vs baseline: 1.6724x; 1.0459x over previous
//
#include <hip/hip_runtime.h>
#include <cstdint>
#include <cstddef>

#define NEG_SLOPE 0.2f

typedef _Float16 f16x8 __attribute__((ext_vector_type(8)));
typedef float f32x4v __attribute__((ext_vector_type(4)));

__device__ __forceinline__ unsigned enc_f(float f) {
  unsigned u = __float_as_uint(f);
  return (u & 0x80000000u) ? ~u : (u | 0x80000000u);
}
__device__ __forceinline__ float dec_f(unsigned u) {
  return (u & 0x80000000u) ? __uint_as_float(u ^ 0x80000000u) : __uint_as_float(~u);
}
__device__ __forceinline__ unsigned short f2bf(float f) {
  unsigned u = __float_as_uint(f);
  unsigned r = u + 0x7fffu + ((u >> 16) & 1u);
  return (unsigned short)(r >> 16);
}
#define BLO(u) __uint_as_float((u) << 16)
#define BHI(u) __uint_as_float((u) & 0xffff0000u)

#define AST 136
#define WST 136
#define HST 132
#define SMEM_BYTES (64 * AST * 2 + 128 * WST * 2)

// ---------------- init: zero 8 partitioned count arrays + maxPart ----------------
__global__ void k_init(int* c, unsigned* maxPart, int N8) {
  int n = blockIdx.x * blockDim.x + threadIdx.x;
  if (n < N8) c[n] = 0;
  if (n < 768) maxPart[n] = 0u;
}

// ---------------- shared fp16-MFMA GEMM body (64-row tile) ----------------
__device__ __forceinline__ void gemm_body(char* smem, float* redmax, int bx,
                                          const float* __restrict__ A,
                                          const float* __restrict__ W,
                                          unsigned short* __restrict__ hb,
                                          const float* __restrict__ asrc,
                                          const float* __restrict__ adst,
                                          float* __restrict__ sv, float* __restrict__ dv,
                                          unsigned* __restrict__ maxSlot, int M) {
  _Float16* Ah = (_Float16*)smem;                       // [64][AST]
  _Float16* Wt = (_Float16*)(smem + 64 * AST * 2);      // [128][WST] transposed W
  float*    hS = (float*)(smem + 64 * AST * 2);         // [64][HST] aliases Wt after mfma
  int t = threadIdx.x;
  int rowbase = bx * 64;

  for (int i = t; i < 64 * 32; i += 256) {
    int r = i >> 5, c4 = (i & 31) << 2;
    int gr = rowbase + r;
    float4 v = make_float4(0.f, 0.f, 0.f, 0.f);
    if (gr < M) v = *(const float4*)&A[(size_t)gr * 128 + c4];
    _Float16 tmp[4] = {(_Float16)v.x, (_Float16)v.y, (_Float16)v.z, (_Float16)v.w};
    *(short4*)&Ah[r * AST + c4] = *(short4*)tmp;
  }
  for (int i = t; i < 128 * 32; i += 256) {
    int r = i >> 5, c4 = (i & 31) << 2;
    float4 v = *(const float4*)&W[(size_t)r * 128 + c4];
    Wt[(c4 + 0) * WST + r] = (_Float16)v.x;
    Wt[(c4 + 1) * WST + r] = (_Float16)v.y;
    Wt[(c4 + 2) * WST + r] = (_Float16)v.z;
    Wt[(c4 + 3) * WST + r] = (_Float16)v.w;
  }
  __syncthreads();

  int wave = t >> 6, lane = t & 63, quad = lane >> 4, l15 = lane & 15;
  f32x4v acc[4][2];
#pragma unroll
  for (int mt = 0; mt < 4; mt++)
#pragma unroll
    for (int nt = 0; nt < 2; nt++) {
      acc[mt][nt][0] = 0.f; acc[mt][nt][1] = 0.f; acc[mt][nt][2] = 0.f; acc[mt][nt][3] = 0.f;
    }

#pragma unroll
  for (int s = 0; s < 4; s++) {
    int k0 = (s << 5) + (quad << 3);
    f16x8 af[4], bf[2];
#pragma unroll
    for (int mt = 0; mt < 4; mt++)
      af[mt] = *(f16x8*)&Ah[(mt * 16 + l15) * AST + k0];
#pragma unroll
    for (int nt = 0; nt < 2; nt++)
      bf[nt] = *(f16x8*)&Wt[(wave * 32 + nt * 16 + l15) * WST + k0];
#pragma unroll
    for (int mt = 0; mt < 4; mt++)
#pragma unroll
      for (int nt = 0; nt < 2; nt++)
        acc[mt][nt] = __builtin_amdgcn_mfma_f32_16x16x32_f16(af[mt], bf[nt], acc[mt][nt], 0, 0, 0);
  }
  __syncthreads();

#pragma unroll
  for (int mt = 0; mt < 4; mt++)
#pragma unroll
    for (int nt = 0; nt < 2; nt++)
#pragma unroll
      for (int rr = 0; rr < 4; rr++)
        hS[(mt * 16 + quad * 4 + rr) * HST + wave * 32 + nt * 16 + l15] = acc[mt][nt][rr];
  __syncthreads();

  int tx = t & 31, ty = t >> 5;
  float4 av  = *(const float4*)&asrc[tx * 4];
  float4 adv = *(const float4*)&adst[tx * 4];
  float wmax = -1e30f;
#pragma unroll
  for (int r8 = 0; r8 < 8; r8++) {
    int row = r8 * 8 + ty;
    int gr = rowbase + row;
    float4 hv = *(float4*)&hS[row * HST + tx * 4];
    float ps = hv.x * av.x + hv.y * av.y + hv.z * av.z + hv.w * av.w;
    float pd = hv.x * adv.x + hv.y * adv.y + hv.z * adv.z + hv.w * adv.w;
#pragma unroll
    for (int mask = 16; mask; mask >>= 1) {
      ps += __shfl_xor(ps, mask);
      pd += __shfl_xor(pd, mask);
    }
    if (gr < M) {
      ushort4 hq;
      hq.x = f2bf(hv.x); hq.y = f2bf(hv.y); hq.z = f2bf(hv.z); hq.w = f2bf(hv.w);
      *(ushort4*)&hb[(size_t)gr * 128 + tx * 4] = hq;
      if (tx == 0) { sv[gr] = ps; dv[gr] = pd; wmax = fmaxf(wmax, ps); }
    }
  }
#pragma unroll
  for (int mask = 32; mask; mask >>= 1) wmax = fmaxf(wmax, __shfl_xor(wmax, mask));
  if ((t & 63) == 0) redmax[t >> 6] = wmax;
  __syncthreads();
  if (t == 0) {
    float mx = fmaxf(fmaxf(redmax[0], redmax[1]), fmaxf(redmax[2], redmax[3]));
    atomicMax(&maxSlot[blockIdx.x & 255], enc_f(mx));
  }
}

// ---------------- MEGA1: count_rank (blocks [0,Gc)) || gemm L0 (blocks [Gc,Gc+Gg)) ---------------
__global__ __launch_bounds__(256) void k_mega1(const float* __restrict__ A,
                                               const float* __restrict__ W,
                                               unsigned short* __restrict__ hb,
                                               const float* __restrict__ asrc,
                                               const float* __restrict__ adst,
                                               float* __restrict__ sv, float* __restrict__ dv,
                                               unsigned* __restrict__ maxSlot, int M,
                                               const int* __restrict__ dst, int E,
                                               int* c, int* __restrict__ rank,
                                               int Gc, int vec4) {
  __shared__ __align__(16) char smem[SMEM_BYTES];
  __shared__ float redmax[4];
  if ((int)blockIdx.x < Gc) {
    int i = (blockIdx.x << 10) + threadIdx.x * 4;
    if (vec4 && i + 3 < E) {
      int p = (i >> 10) & 7;
      int* cp = c + (size_t)p * M;
      int4 d = *(const int4*)&dst[i];
      int4 r;
      r.x = atomicAdd(&cp[d.x], 1);
      r.y = atomicAdd(&cp[d.y], 1);
      r.z = atomicAdd(&cp[d.z], 1);
      r.w = atomicAdd(&cp[d.w], 1);
      *(int4*)&rank[i] = r;
    } else {
      for (int e = i; e < min(i + 4, E); e++) {
        int p = (e >> 10) & 7;
        rank[e] = atomicAdd(&c[(size_t)p * M + dst[e]], 1);
      }
    }
  } else {
    gemm_body(smem, redmax, (int)blockIdx.x - Gc, A, W, hb, asrc, adst, sv, dv, maxSlot, M);
  }
}

// ---------------- plain fused GEMM for layers 1,2 ----------------
__global__ __launch_bounds__(256) void k_gemm_fused(const float* __restrict__ A,
                                                    const float* __restrict__ W,
                                                    unsigned short* __restrict__ hb,
                                                    const float* __restrict__ asrc,
                                                    const float* __restrict__ adst,
                                                    float* __restrict__ sv, float* __restrict__ dv,
                                                    unsigned* __restrict__ maxSlot, int M) {
  __shared__ __align__(16) char smem[SMEM_BYTES];
  __shared__ float redmax[4];
  gemm_body(smem, redmax, (int)blockIdx.x, A, W, hb, asrc, adst, sv, dv, maxSlot, M);
}

// ---------------- scans over total counts (1 self loop + 8 partitions) ----------------
__global__ __launch_bounds__(1024) void k_scan1(const int* __restrict__ c, int N,
                                                int* __restrict__ row_ptr, int* __restrict__ part) {
  __shared__ int tmp[1024];
  int t = threadIdx.x;
  int i = blockIdx.x * 1024 + t;
  int v = 0;
  if (i < N) {
    v = 1;
#pragma unroll
    for (int p = 0; p < 8; p++) v += c[(size_t)p * N + i];
  }
  tmp[t] = v;
  __syncthreads();
  for (int off = 1; off < 1024; off <<= 1) {
    int u = (t >= off) ? tmp[t - off] : 0;
    __syncthreads();
    tmp[t] += u;
    __syncthreads();
  }
  if (i < N) row_ptr[i + 1] = tmp[t];
  if (t == 1023) part[blockIdx.x] = tmp[t];
}

__global__ void k_scan2(int* part, int nb, int* row_ptr) {
  if (threadIdx.x == 0 && blockIdx.x == 0) {
    int run = 0;
    for (int b = 0; b < nb; b++) { int v = part[b]; part[b] = run; run += v; }
    row_ptr[0] = 0;
  }
}

__global__ __launch_bounds__(1024) void k_scan3(int* __restrict__ row_ptr,
                                                const int* __restrict__ part, int N) {
  int i = blockIdx.x * 1024 + threadIdx.x;
  if (i < N) row_ptr[i + 1] += part[blockIdx.x];
}

// per-(partition,node) bases + self-loop placement
__global__ void k_base(const int* __restrict__ row_ptr, const int* __restrict__ c,
                       int* __restrict__ base, int* __restrict__ col, int N) {
  int n = blockIdx.x * blockDim.x + threadIdx.x;
  if (n >= N) return;
  int b = row_ptr[n];
  col[b] = n;  // self loop first
  b++;
#pragma unroll
  for (int p = 0; p < 8; p++) {
    base[(size_t)p * N + n] = b;
    b += c[(size_t)p * N + n];
  }
}

__global__ void k_fill(const int* __restrict__ src, const int* __restrict__ dst,
                       const int* __restrict__ rank, int E, int N,
                       const int* __restrict__ base, int* __restrict__ col, int vec4) {
  int i = (blockIdx.x * blockDim.x + threadIdx.x) * 4;
  if (vec4 && i + 3 < E) {
    int p = (i >> 10) & 7;
    const int* bp = base + (size_t)p * N;
    int4 s = *(const int4*)&src[i];
    int4 d = *(const int4*)&dst[i];
    int4 r = *(const int4*)&rank[i];
    col[bp[d.x] + r.x] = s.x;
    col[bp[d.y] + r.y] = s.y;
    col[bp[d.z] + r.z] = s.z;
    col[bp[d.w] + r.w] = s.w;
  } else {
    for (int e = i; e < min(i + 4, E); e++) {
      int p = (e >> 10) & 7;
      col[base[(size_t)p * N + dst[e]] + rank[e]] = src[e];
    }
  }
}

// ---------------- segment-softmax aggregation: 1 wave/node, 4 groups of 16, 2 edges in flight ----
__global__ __launch_bounds__(256) void k_agg(const unsigned short* __restrict__ hb,
                                             const float* __restrict__ sv,
                                             const float* __restrict__ dv,
                                             const int* __restrict__ row_ptr,
                                             const int* __restrict__ col,
                                             const float* __restrict__ bias,
                                             const unsigned* __restrict__ maxSlot,
                                             float* __restrict__ out, int N, int relu) {
  int wid = (int)((blockIdx.x * (size_t)blockDim.x + threadIdx.x) >> 6);
  int lane = threadIdx.x & 63;
  if (wid >= N) return;

  unsigned mp = max(max(maxSlot[lane], maxSlot[lane + 64]),
                    max(maxSlot[lane + 128], maxSlot[lane + 192]));
#pragma unroll
  for (int off = 32; off; off >>= 1) mp = max(mp, __shfl_xor(mp, off));
  float maxS = dec_f(mp);

  int beg = row_ptr[wid], end = row_ptr[wid + 1];
  float dn = dv[wid];
  float m = maxS + dn;
  m = (m > 0.f) ? m : NEG_SLOPE * m;  // upper bound (leaky_relu monotone)

  int g = lane >> 4, sub = lane & 15;
  const uint32_t* hbu = (const uint32_t*)hb;
  float acc[8];
#pragma unroll
  for (int k = 0; k < 8; k++) acc[k] = 0.f;
  float dsum = 0.f;

  int j = beg + g;
  for (; j + 4 < end; j += 8) {
    int sn0 = col[j];
    int sn1 = col[j + 4];
    float e0 = sv[sn0] + dn;
    float e1 = sv[sn1] + dn;
    e0 = (e0 > 0.f) ? e0 : NEG_SLOPE * e0;
    e1 = (e1 > 0.f) ? e1 : NEG_SLOPE * e1;
    float w0 = __expf(e0 - m);
    float w1 = __expf(e1 - m);
    dsum += w0 + w1;
    uint4 h0 = *(const uint4*)(hbu + (size_t)sn0 * 64 + sub * 4);
    uint4 h1 = *(const uint4*)(hbu + (size_t)sn1 * 64 + sub * 4);
    acc[0] += w0 * BLO(h0.x) + w1 * BLO(h1.x);
    acc[1] += w0 * BHI(h0.x) + w1 * BHI(h1.x);
    acc[2] += w0 * BLO(h0.y) + w1 * BLO(h1.y);
    acc[3] += w0 * BHI(h0.y) + w1 * BHI(h1.y);
    acc[4] += w0 * BLO(h0.z) + w1 * BLO(h1.z);
    acc[5] += w0 * BHI(h0.z) + w1 * BHI(h1.z);
    acc[6] += w0 * BLO(h0.w) + w1 * BLO(h1.w);
    acc[7] += w0 * BHI(h0.w) + w1 * BHI(h1.w);
  }
  if (j < end) {
    int sn = col[j];
    float e = sv[sn] + dn;
    e = (e > 0.f) ? e : NEG_SLOPE * e;
    float wgt = __expf(e - m);
    dsum += wgt;
    uint4 hv = *(const uint4*)(hbu + (size_t)sn * 64 + sub * 4);
    acc[0] += wgt * BLO(hv.x); acc[1] += wgt * BHI(hv.x);
    acc[2] += wgt * BLO(hv.y); acc[3] += wgt * BHI(hv.y);
    acc[4] += wgt * BLO(hv.z); acc[5] += wgt * BHI(hv.z);
    acc[6] += wgt * BLO(hv.w); acc[7] += wgt * BHI(hv.w);
  }
  dsum += __shfl_xor(dsum, 16);
  dsum += __shfl_xor(dsum, 32);
#pragma unroll
  for (int k = 0; k < 8; k++) {
    acc[k] += __shfl_xor(acc[k], 16);
    acc[k] += __shfl_xor(acc[k], 32);
  }
  if (lane < 16) {
    float inv = 1.f / dsum;
    float4 b0 = *(const float4*)&bias[sub * 8];
    float4 b1 = *(const float4*)&bias[sub * 8 + 4];
    float4 o0, o1;
    o0.x = acc[0] * inv + b0.x; o0.y = acc[1] * inv + b0.y;
    o0.z = acc[2] * inv + b0.z; o0.w = acc[3] * inv + b0.w;
    o1.x = acc[4] * inv + b1.x; o1.y = acc[5] * inv + b1.y;
    o1.z = acc[6] * inv + b1.z; o1.w = acc[7] * inv + b1.w;
    if (relu) {
      o0.x = fmaxf(o0.x, 0.f); o0.y = fmaxf(o0.y, 0.f); o0.z = fmaxf(o0.z, 0.f); o0.w = fmaxf(o0.w, 0.f);
      o1.x = fmaxf(o1.x, 0.f); o1.y = fmaxf(o1.y, 0.f); o1.z = fmaxf(o1.z, 0.f); o1.w = fmaxf(o1.w, 0.f);
    }
    float* op = &out[(size_t)wid * 128 + sub * 8];
    *(float4*)op = o0;
    *(float4*)(op + 4) = o1;
  }
}

// ---------------- batch boundaries (batch is sorted) ----------------
__global__ void k_bounds(const int* __restrict__ batch, int N, int B, int* __restrict__ gstart) {
  int n = blockIdx.x * blockDim.x + threadIdx.x;
  if (n >= N) return;
  int cur = batch[n];
  if (n == 0) {
    for (int g = 0; g <= cur; g++) gstart[g] = 0;
  } else {
    int prev = batch[n - 1];
    for (int g = prev + 1; g <= cur; g++) gstart[g] = n;
  }
  if (n == N - 1) {
    for (int g = cur + 1; g <= B; g++) gstart[g] = N;
  }
}

// ---------------- mean pool + relu ----------------
__global__ __launch_bounds__(128) void k_pool(const float* __restrict__ h,
                                              const int* __restrict__ gstart,
                                              float* __restrict__ pooled, int B) {
  int b = blockIdx.x, c = threadIdx.x;
  int s0 = gstart[b], s1 = gstart[b + 1];
  float acc = 0.f;
  for (int n = s0; n < s1; n++) acc += h[(size_t)n * 128 + c];
  int cnt = s1 - s0;
  float p = acc / (float)(cnt > 0 ? cnt : 1);
  pooled[b * 128 + c] = fmaxf(p, 0.f);
}

// ---------------- fused MLP head ----------------
__global__ __launch_bounds__(256) void k_mlp(const float* __restrict__ pooled,
                                             const float* __restrict__ Wf1,
                                             const float* __restrict__ bf1,
                                             const float* __restrict__ Wf2,
                                             const float* __restrict__ bf2,
                                             float* __restrict__ out, int B) {
  __shared__ float P[4][128];
  __shared__ float H1[4][1024];
  __shared__ float R[4][128];
  int t = threadIdx.x;
  int g0 = blockIdx.x * 4;

  for (int i = t; i < 4 * 128; i += 256) {
    int gi = i >> 7, c = i & 127;
    P[gi][c] = (g0 + gi < B) ? pooled[(size_t)(g0 + gi) * 128 + c] : 0.f;
  }
  __syncthreads();

#pragma unroll
  for (int cb = 0; cb < 4; cb++) {
    int c = cb * 256 + t;
    float a0 = 0.f, a1 = 0.f, a2 = 0.f, a3 = 0.f;
    for (int k = 0; k < 128; k++) {
      float w = Wf1[(size_t)k * 1024 + c];
      a0 += P[0][k] * w; a1 += P[1][k] * w; a2 += P[2][k] * w; a3 += P[3][k] * w;
    }
    float b = bf1[c];
    H1[0][c] = fmaxf(a0 + b, 0.f);
    H1[1][c] = fmaxf(a1 + b, 0.f);
    H1[2][c] = fmaxf(a2 + b, 0.f);
    H1[3][c] = fmaxf(a3 + b, 0.f);
  }
  __syncthreads();

  int c = t & 127, hh = t >> 7;
  float a0 = 0.f, a1 = 0.f, a2 = 0.f, a3 = 0.f;
  int k0 = hh * 512;
  for (int k = k0; k < k0 + 512; k++) {
    float w = Wf2[(size_t)k * 128 + c];
    a0 += H1[0][k] * w; a1 += H1[1][k] * w; a2 += H1[2][k] * w; a3 += H1[3][k] * w;
  }
  if (hh == 1) { R[0][c] = a0; R[1][c] = a1; R[2][c] = a2; R[3][c] = a3; }
  __syncthreads();
  if (hh == 0) {
    float b = bf2[c];
    float o0 = a0 + R[0][c] + b;
    float o1 = a1 + R[1][c] + b;
    float o2 = a2 + R[2][c] + b;
    float o3 = a3 + R[3][c] + b;
    if (g0 + 0 < B) out[(size_t)(g0 + 0) * 128 + c] = o0;
    if (g0 + 1 < B) out[(size_t)(g0 + 1) * 128 + c] = o1;
    if (g0 + 2 < B) out[(size_t)(g0 + 2) * 128 + c] = o2;
    if (g0 + 3 < B) out[(size_t)(g0 + 3) * 128 + c] = o3;
  }
}

extern "C" void kernel_launch(void* const* d_in, const int* in_sizes, int n_in,
                              void* d_out, int out_size, void* d_ws, size_t ws_size,
                              hipStream_t stream) {
  const float* x     = (const float*)d_in[0];
  const int*   ei    = (const int*)d_in[1];
  const int*   batch = (const int*)d_in[3];
  const float* W1 = (const float*)d_in[4];
  const float* as1 = (const float*)d_in[5];
  const float* ad1 = (const float*)d_in[6];
  const float* b1 = (const float*)d_in[7];
  const float* W2 = (const float*)d_in[8];
  const float* as2 = (const float*)d_in[9];
  const float* ad2 = (const float*)d_in[10];
  const float* b2 = (const float*)d_in[11];
  const float* W3 = (const float*)d_in[12];
  const float* as3 = (const float*)d_in[13];
  const float* ad3 = (const float*)d_in[14];
  const float* b3 = (const float*)d_in[15];
  const float* Wf1 = (const float*)d_in[16];
  const float* bf1 = (const float*)d_in[17];
  const float* Wf2 = (const float*)d_in[18];
  const float* bf2 = (const float*)d_in[19];

  const int N = in_sizes[0] / 128;
  const int E = in_sizes[1] / 2;
  const int B = out_size / 128;

  char* base_ws = (char*)d_ws;
  size_t off = 0;
  auto carve = [&](size_t bytes) -> void* {
    off = (off + 255) & ~(size_t)255;
    void* p = base_ws + off;
    off += bytes;
    return p;
  };
  int* c        = (int*)carve((size_t)8 * N * 4);
  int* base     = (int*)carve((size_t)8 * N * 4);
  int* row_ptr  = (int*)carve((size_t)(N + 1) * 4);
  int* rank     = (int*)carve((size_t)E * 4);
  int* col      = (int*)carve((size_t)(E + N) * 4);
  int* part     = (int*)carve(1024 * 4);
  int* gstart   = (int*)carve((size_t)(B + 1) * 4);
  unsigned* maxPart = (unsigned*)carve(768 * 4);
  float* sbuf   = (float*)carve((size_t)N * 4);
  float* dbuf   = (float*)carve((size_t)N * 4);
  unsigned short* hb = (unsigned short*)carve((size_t)N * 128 * 2);
  float* abuf   = (float*)carve((size_t)N * 128 * 4);
  float* pooled = (float*)carve((size_t)B * 128 * 4);

  const int* srcp = ei;
  const int* dstp = ei + E;
  const int nb = (N + 1023) / 1024;
  const int Gc = (E + 1023) >> 10;          // count blocks (1024 edges each)
  const int Gg = (N + 63) / 64;             // gemm L0 blocks
  const int vec4 = ((E & 3) == 0) ? 1 : 0;  // int4 alignment of dstp/srcp

  hipLaunchKernelGGL(k_init, dim3((8 * N + 255) / 256), dim3(256), 0, stream, c, maxPart, 8 * N);
  hipLaunchKernelGGL(k_bounds, dim3((N + 255) / 256), dim3(256), 0, stream, batch, N, B, gstart);

  // count_rank || gemm L0
  hipLaunchKernelGGL(k_mega1, dim3(Gc + Gg), dim3(256), 0, stream,
                     x, W1, hb, as1, ad1, sbuf, dbuf, maxPart + 0 * 256, N,
                     dstp, E, c, rank, Gc, vec4);

  hipLaunchKernelGGL(k_scan1, dim3(nb), dim3(1024), 0, stream, c, N, row_ptr, part);
  hipLaunchKernelGGL(k_scan2, dim3(1), dim3(64), 0, stream, part, nb, row_ptr);
  hipLaunchKernelGGL(k_scan3, dim3(nb), dim3(1024), 0, stream, row_ptr, part, N);
  hipLaunchKernelGGL(k_base, dim3((N + 255) / 256), dim3(256), 0, stream, row_ptr, c, base, col, N);
  hipLaunchKernelGGL(k_fill, dim3((E + 1023) / 1024), dim3(256), 0, stream,
                     srcp, dstp, rank, E, N, base, col, vec4);

  hipLaunchKernelGGL(k_agg, dim3((N + 3) / 4), dim3(256), 0, stream,
                     hb, sbuf, dbuf, row_ptr, col, b1, maxPart + 0 * 256, abuf, N, 0);

  const float* Wl[3] = {W1, W2, W3};
  const float* al[3] = {as1, as2, as3};
  const float* dl[3] = {ad1, ad2, ad3};
  const float* bl[3] = {b2, b3, b3};
  for (int L = 1; L < 3; L++) {
    const float* Ws = Wl[L];
    hipLaunchKernelGGL(k_gemm_fused, dim3((N + 63) / 64), dim3(256), 0, stream,
                       abuf, Ws, hb, al[L], dl[L], sbuf, dbuf, maxPart + L * 256, N);
    hipLaunchKernelGGL(k_agg, dim3((N + 3) / 4), dim3(256), 0, stream,
                       hb, sbuf, dbuf, row_ptr, col, (L == 1) ? b2 : b3, maxPart + L * 256, abuf, N, 1);
  }

  hipLaunchKernelGGL(k_pool, dim3(B), dim3(128), 0, stream, abuf, gstart, pooled, B);
  hipLaunchKernelGGL(k_mlp, dim3((B + 3) / 4), dim3(256), 0, stream,
                     pooled, Wf1, bf1, Wf2, bf2, (float*)d_out, B);
}